// Round 17
// baseline (98.180 us; speedup 1.0000x reference)
//
#include <hip/hip_runtime.h>
#include <hip/hip_bf16.h>
#include <stdint.h>
#include <math.h>

// DynaLoRALinear bf16-MFMA.
// prep(weights) -> gemm_h(BM=64xBN=256, 2 blocks/CU, fused x-convert + partial
// router logits) -> gemm_w(sum 2 slices + softmax) -> gemm_out(256^2 8-phase).
// out = [x|w] @ [Wb^T;B2], K=1088.  GEMMs take K runtime (anti-unroll, r12).

#define M_TOK 16384

typedef unsigned short u16;
typedef short bf16x8 __attribute__((ext_vector_type(8)));
typedef float f32x4 __attribute__((ext_vector_type(4)));
typedef __attribute__((address_space(3))) uint32_t lds_u32_t;
typedef __attribute__((address_space(1))) const uint32_t glb_u32_t;

__device__ __forceinline__ u16 f2bf(float f) {
  uint32_t u = __builtin_bit_cast(uint32_t, f);
  return (u16)((u + 0x7fffu + ((u >> 16) & 1u)) >> 16);  // RNE
}
__device__ __forceinline__ int cvtpk(float lo, float hi) {  // RNE packed bf16
  int r;
  asm("v_cvt_pk_bf16_f32 %0, %1, %2" : "=v"(r) : "v"(lo), "v"(hi));
  return r;
}

#define VMCNT(n) asm volatile("s_waitcnt vmcnt(%0)" ::"i"(n) : "memory")
#define LGKM0 asm volatile("s_waitcnt lgkmcnt(0)" ::: "memory")
#define BAR asm volatile("s_barrier" ::: "memory")
#define MEMFENCE asm volatile("" ::: "memory")
#define SP(x) __builtin_amdgcn_s_setprio(x)

// ---------------- prep: weight conversions + gathers only (~9 MB) ----------------
__global__ __launch_bounds__(256) void prep_k(const float* __restrict__ Wb,
                                              const float* __restrict__ rW1,
                                              const float* __restrict__ rW2,
                                              const float* __restrict__ loraA,
                                              const float* __restrict__ loraB,
                                              u16* __restrict__ Btb,
                                              u16* __restrict__ W1b,
                                              u16* __restrict__ W2b,
                                              u16* __restrict__ A2b) {
  const int g = blockIdx.x;
  const int tid = threadIdx.x;
  if (g < 1024) {  // Wb -> Btb cols 0..1023 (stride 1088)
    int i = g * 256 + tid;
    int idx = i * 4;
    int row = idx >> 10, col = idx & 1023;
    float4 v = ((const float4*)Wb)[i];
    ushort4 o;
    o.x = f2bf(v.x); o.y = f2bf(v.y); o.z = f2bf(v.z); o.w = f2bf(v.w);
    *(ushort4*)(Btb + (size_t)row * 1088 + col) = o;
  } else if (g < 1536) {  // rW1 -> W1b
    int i = (g - 1024) * 256 + tid;
    float4 v = ((const float4*)rW1)[i];
    ushort4 o;
    o.x = f2bf(v.x); o.y = f2bf(v.y); o.z = f2bf(v.z); o.w = f2bf(v.w);
    ((ushort4*)W1b)[i] = o;
  } else if (g < 1792) {  // lora_B gather -> Btb cols 1024..1087
    int idx = (g - 1536) * 256 + tid;
    int n = idx >> 6, q = idx & 63;
    int e = q >> 3, r = q & 7;
    Btb[(size_t)n * 1088 + 1024 + q] = f2bf(loraB[((size_t)(e * 1024 + n)) * 8 + r]);
  } else if (g < 1856) {  // loraA -> A2b
    int i = (g - 1792) * 256 + tid;
    float4 v = ((const float4*)loraA)[i];
    ushort4 o;
    o.x = f2bf(v.x); o.y = f2bf(v.y); o.z = f2bf(v.z); o.w = f2bf(v.w);
    ((ushort4*)A2b)[i] = o;
  } else {  // W2b [16][512] bf16, rows 8..15 zero
    int i = (g - 1856) * 256 + tid;
    int idx = i * 4;
    int row = idx >> 9, col = idx & 511;
    ushort4 o = {0, 0, 0, 0};
    if (row < 8) {
      float4 v = *(const float4*)(rW2 + (size_t)row * 512 + col);
      o.x = f2bf(v.x); o.y = f2bf(v.y); o.z = f2bf(v.z); o.w = f2bf(v.w);
    }
    ((ushort4*)W2b)[i] = o;
  }
}

// ============ gemm_h: BM=64 x BN=256, 2 blocks/CU, fused x-convert + router ============
// 512 blocks (idx pairs share m-panel; n0 = 0 or 256). 8 waves; wave w owns cols
// w*32..+31 (4x2 frags, 16 MFMA/tile). LDS 80 KB -> 2 blocks/CU (TLP hides the
// per-tile serial chain that kept 1-block/CU variants at MfmaUtil 13%).
// FIFO audit/tile: enter [x(t+1):2,S:1]; +B:4 +x:2 -> VMCNT(6) completes
// x(t+1)+S; +S -> VMCNT(3) completes B(t+1). Both half-N twins convert x and
// store identical xb bytes (idempotent; keeps counts uniform).
// Epilogue: partial logits over this block's 256 cols -> part[n0>>8][M][8].
__global__ __launch_bounds__(512, 2) void gemm_h(const float* __restrict__ x,
                                                 const u16* __restrict__ W1b,
                                                 const u16* __restrict__ W2bv,
                                                 u16* __restrict__ xb,
                                                 float* __restrict__ part,
                                                 const float* __restrict__ b1,
                                                 const int K) {
  constexpr int ABUF = 64 * 128;           // 8 KB
  constexpr int BBUF = 256 * 128;          // 32 KB
  constexpr int BUFB = ABUF + BBUF;        // 40 KB
  __shared__ __align__(16) uint8_t lds[2 * BUFB];  // 80 KB

  const int tid = threadIdx.x;
  const int lane = tid & 63, w = tid >> 6;
  const int l15 = lane & 15, lhi = lane >> 4;
  const int xorv = (lane & 7) << 4;
  const int c0 = (lhi * 16) ^ xorv;
  const int c1 = (64 + lhi * 16) ^ xorv;

  const int f = blockIdx.x;                      // 512 blocks
  const int idx = (f & 7) * 64 + (f >> 3);       // XCD swizzle
  const int m0 = (idx >> 1) * 64;
  const int n0 = (idx & 1) * 256;

  const int nk = K >> 6;                         // 16
  const int rot = (f >> 3) & (nk - 1);
  auto PH = [&](int l) { int lc = l < nk ? l : nk - 1; return (lc + rot) & (nk - 1); };

  const int xrow = tid >> 3, xsub = tid & 7;     // 64 rows x 8 subs

  f32x4 acc[4][2] = {};
  bf16x8 af[4][2], bfv[2][2];
  float4 xA0, xA1, xB0, xB1;

  auto stageBH = [&](int ktp, int b) {
    uint8_t* dst = lds + b * BUFB + ABUF + w * 1024;
#pragma unroll
    for (int i = 0; i < 4; ++i) {
      const int off = i * 8192 + tid * 16;
      const int row = off >> 7;                  // 0..255
      const int ss = ((off >> 4) & 7) ^ (row & 7);
      const uint8_t* g =
          (const uint8_t*)W1b + (size_t)(n0 + row) * 2048 + ktp * 128 + ss * 16;
      __builtin_amdgcn_global_load_lds((glb_u32_t*)g, (lds_u32_t*)(dst + i * 8192),
                                       16, 0, 0);
    }
  };
  auto issueX = [&](int ktp, float4& ra, float4& rb) {
    const float* gp = x + (size_t)(m0 + xrow) * 1024 + ktp * 64 + xsub * 8;
    ra = *(const float4*)gp;
    rb = *(const float4*)(gp + 4);
  };
  auto writeA = [&](int ktp, int b, const float4& ra, const float4& rb) {
    int4 sv;
    sv.x = cvtpk(ra.x, ra.y); sv.y = cvtpk(ra.z, ra.w);
    sv.z = cvtpk(rb.x, rb.y); sv.w = cvtpk(rb.z, rb.w);
    *(int4*)(lds + b * BUFB + xrow * 128 + ((xsub ^ (xrow & 7)) << 4)) = sv;
    *(int4*)(xb + (size_t)(m0 + xrow) * 1024 + ktp * 64 + xsub * 8) = sv;
  };
  auto loadAH = [&](const uint8_t* bufA) {
#pragma unroll
    for (int mf = 0; mf < 4; ++mf) {
      const uint8_t* pr = bufA + (mf * 16 + l15) * 128;
      af[mf][0] = *(const bf16x8*)(pr + c0);
      af[mf][1] = *(const bf16x8*)(pr + c1);
    }
  };
  auto loadBH = [&](const uint8_t* bufB) {
#pragma unroll
    for (int nf = 0; nf < 2; ++nf) {
      const uint8_t* pr = bufB + (w * 32 + nf * 16 + l15) * 128;
      bfv[nf][0] = *(const bf16x8*)(pr + c0);
      bfv[nf][1] = *(const bf16x8*)(pr + c1);
    }
  };

#define HMM()                                                                  \
  _Pragma("unroll") for (int mf = 0; mf < 4; ++mf)                             \
  _Pragma("unroll") for (int nf = 0; nf < 2; ++nf)                             \
  _Pragma("unroll") for (int ks = 0; ks < 2; ++ks)                             \
      acc[mf][nf] = __builtin_amdgcn_mfma_f32_16x16x32_bf16(                   \
          af[mf][ks], bfv[nf][ks], acc[mf][nf], 0, 0, 0);

  // ---- prologue: A(rot)->buf0 (convert), B(rot)->buf0, issue x(next)->xA ----
  {
    const float* gp = x + (size_t)(m0 + xrow) * 1024 + rot * 64 + xsub * 8;
    float4 a = *(const float4*)gp, b = *(const float4*)(gp + 4);
    int4 sv;
    sv.x = cvtpk(a.x, a.y); sv.y = cvtpk(a.z, a.w);
    sv.z = cvtpk(b.x, b.y); sv.w = cvtpk(b.z, b.w);
    *(int4*)(lds + xrow * 128 + ((xsub ^ (xrow & 7)) << 4)) = sv;
    *(int4*)(xb + (size_t)(m0 + xrow) * 1024 + rot * 64 + xsub * 8) = sv;
  }
  stageBH(rot, 0);
  MEMFENCE;
  issueX(PH(1), xA0, xA1);
  VMCNT(2);  // completes S + B(0):4; leaves x(1):2
  LGKM0;
  BAR;

  const int nit = nk >> 1;
#pragma unroll 1
  for (int it = 0; it < nit; ++it) {
    const int t = it * 2;
    // ---- even tile t: p=buf0, q=buf1 ----
    loadAH(lds);
    loadBH(lds + ABUF);
    stageBH(PH(t + 1), 1);
    MEMFENCE;
    issueX(PH(t + 2), xB0, xB1);
    MEMFENCE;
    VMCNT(6);               // completes x(t+1)+S(t); leaves B(t+1):4 + x(t+2):2
    writeA(PH(t + 1), 1, xA0, xA1);
    SP(1); HMM(); SP(0);
    LGKM0; VMCNT(3); BAR;   // completes B(t+1); leaves x(t+2):2 + S(t+1):1
    // ---- odd tile t+1: p=buf1, q=buf0 ----
    loadAH(lds + BUFB);
    loadBH(lds + BUFB + ABUF);
    stageBH(PH(t + 2), 0);
    MEMFENCE;
    issueX(PH(t + 3), xA0, xA1);
    MEMFENCE;
    VMCNT(6);
    writeA(PH(t + 2), 0, xB0, xB1);
    SP(1); HMM(); SP(0);
    LGKM0; VMCNT(3); BAR;
  }

  // ---- epilogue: spill relu(h+b1) -> hs[64][264], partial router logits ----
  u16* hs = (u16*)lds;
  __syncthreads();  // drains in-flight clamped prefetches + barrier
#pragma unroll
  for (int mf = 0; mf < 4; ++mf) {
#pragma unroll
    for (int nf = 0; nf < 2; ++nf) {
      const int col = w * 32 + nf * 16 + l15;   // block-local col
#pragma unroll
      for (int j = 0; j < 4; ++j) {
        const int row = mf * 16 + lhi * 4 + j;
        float v = fmaxf(acc[mf][nf][j] + b1[n0 + col], 0.f);
        hs[row * 264 + col] = f2bf(v);
      }
    }
  }
  __syncthreads();
  if (w < 4) {  // wave w: rows w*16..+15, K=256 (this block's half)
    f32x4 acc2 = {};
#pragma unroll
    for (int ks = 0; ks < 8; ++ks) {
      bf16x8 bfrag = *(const bf16x8*)(W2bv + (size_t)l15 * 512 + n0 + ks * 32 + lhi * 8);
      bf16x8 afrag = *(const bf16x8*)(hs + (w * 16 + l15) * 264 + ks * 32 + lhi * 8);
      acc2 = __builtin_amdgcn_mfma_f32_16x16x32_bf16(afrag, bfrag, acc2, 0, 0, 0);
    }
    if (l15 < 8) {
      const size_t base = (size_t)(n0 >> 8) * M_TOK;
#pragma unroll
      for (int j = 0; j < 4; ++j) {
        const int row = m0 + w * 16 + lhi * 4 + j;
        part[(base + row) * 8 + l15] = acc2[j];
      }
    }
  }
}

// ---------------- w-GEMM with fused gate softmax (2 partial slices) ----------------
__global__ __launch_bounds__(256) void gemm_w(const u16* __restrict__ A,
                                              const u16* __restrict__ Bt,
                                              const float* __restrict__ part,
                                              const float* __restrict__ b2,
                                              const float* __restrict__ temp,
                                              u16* __restrict__ Cv) {
  constexpr int BM = 64, BN = 64, FM = 2, FN = 2, AI = 2, BI = 2;
  __shared__ u16 lds[(BM + BN) * 64];
  __shared__ float g_lds[64][8];
  u16* As = lds;
  u16* Bs = lds + BM * 64;

  const int tid = threadIdx.x;
  const int w = tid >> 6, lane = tid & 63;
  const int wr = w >> 1, wc = w & 1;
  const int m0 = blockIdx.y * BM;

  if (tid < 64) {
    const int m = m0 + tid;
    float lg[8] = {};
#pragma unroll
    for (int q = 0; q < 2; ++q) {
      const float4* pp = (const float4*)(part + ((size_t)q * M_TOK + m) * 8);
      float4 a = pp[0], b = pp[1];
      lg[0] += a.x; lg[1] += a.y; lg[2] += a.z; lg[3] += a.w;
      lg[4] += b.x; lg[5] += b.y; lg[6] += b.z; lg[7] += b.w;
    }
    float t = temp[0], mx = -1e30f;
#pragma unroll
    for (int e = 0; e < 8; ++e) { lg[e] = (lg[e] + b2[e]) / t; mx = fmaxf(mx, lg[e]); }
    float s = 0.f;
#pragma unroll
    for (int e = 0; e < 8; ++e) { lg[e] = expf(lg[e] - mx); s += lg[e]; }
    float inv = 1.f / s;
#pragma unroll
    for (int e = 0; e < 8; ++e) g_lds[tid][e] = lg[e] * inv;
  }

  const uint8_t* Ab = (const uint8_t*)A;
  const uint8_t* Bb = (const uint8_t*)Bt;
  f32x4 acc[FM][FN] = {};

  for (int kt = 0; kt < 16; ++kt) {
#pragma unroll
    for (int i = 0; i < AI; ++i) {
      const int lbase = (w * AI + i) * 1024;
      const int o = lbase + lane * 16;
      const int r = o >> 7, cb = o & 127;
      const uint8_t* g = Ab + (size_t)(m0 + r) * 2048 + (size_t)kt * 128 + cb;
      __builtin_amdgcn_global_load_lds((glb_u32_t*)g,
                                       (lds_u32_t*)((uint8_t*)As + lbase), 16, 0, 0);
    }
#pragma unroll
    for (int i = 0; i < BI; ++i) {
      const int lbase = (w * BI + i) * 1024;
      const int o = lbase + lane * 16;
      const int r = o >> 7, cb = o & 127;
      const uint8_t* g = Bb + (size_t)r * 2048 + (size_t)kt * 128 + cb;
      __builtin_amdgcn_global_load_lds((glb_u32_t*)g,
                                       (lds_u32_t*)((uint8_t*)Bs + lbase), 16, 0, 0);
    }
    __syncthreads();

    bf16x8 af[2][FM], bfv[2][FN];
#pragma unroll
    for (int ks = 0; ks < 2; ++ks) {
      const int col = ks * 32 + ((lane >> 4) << 3);
#pragma unroll
      for (int im = 0; im < FM; ++im) {
        const int row = wr * 32 + im * 16 + (lane & 15);
        af[ks][im] = *(const bf16x8*)(As + row * 64 + col);
      }
#pragma unroll
      for (int in_ = 0; in_ < FN; ++in_) {
        const int row = wc * 32 + in_ * 16 + (lane & 15);
        bfv[ks][in_] = *(const bf16x8*)(Bs + row * 64 + col);
      }
    }
#pragma unroll
    for (int ks = 0; ks < 2; ++ks)
#pragma unroll
      for (int im = 0; im < FM; ++im)
#pragma unroll
        for (int in_ = 0; in_ < FN; ++in_)
          acc[im][in_] = __builtin_amdgcn_mfma_f32_16x16x32_bf16(
              af[ks][im], bfv[ks][in_], acc[im][in_], 0, 0, 0);
    __syncthreads();
  }

#pragma unroll
  for (int im = 0; im < FM; ++im)
#pragma unroll
    for (int in_ = 0; in_ < FN; ++in_) {
      const int col = wc * 32 + in_ * 16 + (lane & 15);
#pragma unroll
      for (int j = 0; j < 4; ++j) {
        const int lrow = wr * 32 + im * 16 + ((lane >> 4) << 2) + j;
        float v = acc[im][in_][j] * g_lds[lrow][col >> 3];
        Cv[(size_t)(m0 + lrow) * 64 + col] = f2bf(v);
      }
    }
}

// ============ gemm_out: r13-proven 8-phase 256^2 (runtime args, rolled loop) ============
#define MFMA_Q2(mh, nh, AF, BF)                                                \
  _Pragma("unroll") for (int im2 = 0; im2 < 4; ++im2)                          \
  _Pragma("unroll") for (int in2 = 0; in2 < 2; ++in2)                          \
  _Pragma("unroll") for (int ks = 0; ks < 2; ++ks)                             \
      acc[(mh) * 4 + im2][(nh) * 2 + in2] =                                    \
          __builtin_amdgcn_mfma_f32_16x16x32_bf16(                             \
              AF[im2][ks], BF[in2][ks],                                        \
              acc[(mh) * 4 + im2][(nh) * 2 + in2], 0, 0, 0);

__global__ __launch_bounds__(512, 2) void gemm_out(const u16* __restrict__ A,
                                                   const u16* __restrict__ Bt,
                                                   const u16* __restrict__ A2,
                                                   float* __restrict__ C,
                                                   const int N, const int K,
                                                   const int lda, const int ldb) {
  constexpr int BM = 256, BN = 256;
  constexpr int VMC = 4;
  constexpr int BUFB = (BM + BN) * 128;

  __shared__ __align__(16) uint8_t lds[2 * BUFB];

  const int tid = threadIdx.x;
  const int lane = tid & 63, w = tid >> 6;
  const int wr = w >> 2, wcn = w & 3;
  const int l15 = lane & 15, lhi = lane >> 4;
  const int xorv = (lane & 7) << 4;
  const int c0 = (lhi * 16) ^ xorv;
  const int c1 = (64 + lhi * 16) ^ xorv;

  const int f = blockIdx.x;
  const int idx = (f & 7) * 32 + (f >> 3);
  const int gx = N / BN;
  const int m0 = (idx / gx) * BM;
  const int n0 = (idx % gx) * BN;

  const size_t lda_b = (size_t)lda * 2, ldb_b = (size_t)ldb * 2;
  const int nk = K >> 6;
  const int arow0 = (wr * (BM / 2) + l15) * 128;
  const int brow0 = (wcn * (BN / 4) + l15) * 128;

  f32x4 acc[8][4] = {};
  bf16x8 A0f[4][2], A1f[4][2];
  bf16x8 B0f[2][2], B1f[2][2];

  auto stageA = [&](int h, int kt, int b) {
    const int ktc = kt < nk ? kt : nk - 1;
    const bool last = (ktc == nk - 1);
    uint8_t* dst = lds + b * BUFB + h * (BM * 64) + w * 1024;
#pragma unroll
    for (int i = 0; i < 2; ++i) {
      const int off = i * 8192 + tid * 16;
      const int row = h * (BM / 2) + (off >> 7);
      const int ss = ((off >> 4) & 7) ^ (row & 7);
      const uint8_t* g =
          last ? (const uint8_t*)A2 + (size_t)(m0 + row) * 128 + ss * 16
               : (const uint8_t*)A + (size_t)(m0 + row) * lda_b + ktc * 128 + ss * 16;
      __builtin_amdgcn_global_load_lds((glb_u32_t*)g, (lds_u32_t*)(dst + i * 8192),
                                       16, 0, 0);
    }
  };
  auto stageB = [&](int h, int kt, int b) {
    const int ktc = kt < nk ? kt : nk - 1;
    uint8_t* dst = lds + b * BUFB + BM * 128 + h * (BN * 64) + w * 1024;
#pragma unroll
    for (int i = 0; i < 2; ++i) {
      const int off = i * 8192 + tid * 16;
      const int row = h * (BN / 2) + (off >> 7);
      const int ss = ((off >> 4) & 7) ^ (row & 7);
      const uint8_t* g =
          (const uint8_t*)Bt + (size_t)(n0 + row) * ldb_b + ktc * 128 + ss * 16;
      __builtin_amdgcn_global_load_lds((glb_u32_t*)g, (lds_u32_t*)(dst + i * 8192),
                                       16, 0, 0);
    }
  };
  auto loadA = [&](int mh, const uint8_t* buf, bf16x8 (&dst)[4][2]) {
#pragma unroll
    for (int im2 = 0; im2 < 4; ++im2) {
      const uint8_t* p = buf + arow0 + mh * (4 * 2048) + im2 * 2048;
      dst[im2][0] = *(const bf16x8*)(p + c0);
      dst[im2][1] = *(const bf16x8*)(p + c1);
    }
  };
  auto loadB = [&](int nh, const uint8_t* buf, bf16x8 (&dst)[2][2]) {
#pragma unroll
    for (int in2 = 0; in2 < 2; ++in2) {
      const uint8_t* p = buf + BM * 128 + brow0 + nh * (2 * 2048) + in2 * 2048;
      dst[in2][0] = *(const bf16x8*)(p + c0);
      dst[in2][1] = *(const bf16x8*)(p + c1);
    }
  };

  const uint8_t* b0 = lds;
  const uint8_t* b1 = lds + BUFB;

  stageA(0, 0, 0); stageA(1, 0, 0);
  stageB(0, 0, 0); stageB(1, 0, 0);
  stageB(0, 1, 1); stageB(1, 1, 1);
  VMCNT(VMC); BAR;
  loadA(0, b0, A0f); loadB(0, b0, B0f);

  const int NIT = nk >> 1;
#pragma unroll 1
  for (int it = 0; it < NIT; ++it) {
    const int t = it * 2;
    // P1
    stageA(0, t + 1, 1);
    BAR;
    SP(1); MFMA_Q2(0, 0, A0f, B0f); SP(0);
    loadB(1, b0, B1f);
    BAR;
    // P2
    stageA(1, t + 1, 1);
    BAR;
    SP(1); MFMA_Q2(0, 1, A0f, B1f); SP(0);
    loadA(1, b0, A1f);
    BAR;
    // P3
    stageB(0, t + 2, 0);
    BAR;
    SP(1); MFMA_Q2(1, 1, A1f, B1f); SP(0);
    BAR;
    // P4
    stageB(1, t + 2, 0);
    VMCNT(VMC);
    BAR;
    SP(1); MFMA_Q2(1, 0, A1f, B0f); SP(0);
    loadA(0, b1, A0f); loadB(0, b1, B0f);
    BAR;
    // P5
    stageA(0, t + 2, 0);
    BAR;
    SP(1); MFMA_Q2(0, 0, A0f, B0f); SP(0);
    loadB(1, b1, B1f);
    BAR;
    // P6
    stageA(1, t + 2, 0);
    BAR;
    SP(1); MFMA_Q2(0, 1, A0f, B1f); SP(0);
    loadA(1, b1, A1f);
    BAR;
    // P7
    stageB(0, t + 3, 1);
    BAR;
    SP(1); MFMA_Q2(1, 1, A1f, B1f); SP(0);
    BAR;
    // P8
    stageB(1, t + 3, 1);
    VMCNT(VMC);
    BAR;
    SP(1); MFMA_Q2(1, 0, A1f, B0f); SP(0);
    loadA(0, b0, A0f); loadB(0, b0, B0f);
    BAR;
  }

  // tail K-tile (odd nk): buf0 holds tile nk-1; A0f/B0f pre-read at last P8
  if (nk & 1) {
    SP(1); MFMA_Q2(0, 0, A0f, B0f); SP(0);
    loadB(1, b0, B1f);
    SP(1); MFMA_Q2(0, 1, A0f, B1f); SP(0);
    loadA(1, b0, A1f);
    SP(1); MFMA_Q2(1, 1, A1f, B1f); MFMA_Q2(1, 0, A1f, B0f); SP(0);
  }

  // epilogue: plain f32 stores, C/D map col=lane&15, row=(lane>>4)*4+j
#pragma unroll
  for (int im = 0; im < 8; ++im) {
#pragma unroll
    for (int in_ = 0; in_ < 4; ++in_) {
      const int col = n0 + wcn * 64 + in_ * 16 + l15;
#pragma unroll
      for (int j = 0; j < 4; ++j) {
        const int row = m0 + wr * 128 + im * 16 + lhi * 4 + j;
        C[(size_t)row * N + col] = acc[im][in_][j];
      }
    }
  }
}

extern "C" void kernel_launch(void* const* d_in, const int* in_sizes, int n_in,
                              void* d_out, int out_size, void* d_ws, size_t ws_size,
                              hipStream_t stream) {
  const float* x     = (const float*)d_in[0];  // [16384][1024]
  const float* Wb    = (const float*)d_in[1];  // [1024][1024]
  const float* rW1   = (const float*)d_in[2];  // [512][1024]
  const float* rb1   = (const float*)d_in[3];  // [512]
  const float* rW2   = (const float*)d_in[4];  // [8][512]
  const float* rb2   = (const float*)d_in[5];  // [8]
  const float* temp  = (const float*)d_in[6];  // [1]
  const float* loraA = (const float*)d_in[7];  // [64][1024]
  const float* loraB = (const float*)d_in[8];  // [8][1024][8]
  float* out = (float*)d_out;

  uint8_t* p = (uint8_t*)d_ws;
  u16* xb    = (u16*)p;   p += (size_t)M_TOK * 1024 * 2;
  u16* wb    = (u16*)p;   p += (size_t)M_TOK * 64 * 2;
  u16* Btb   = (u16*)p;   p += (size_t)1024 * 1088 * 2;
  u16* W1b   = (u16*)p;   p += (size_t)512 * 1024 * 2;
  u16* W2b   = (u16*)p;   p += (size_t)16 * 512 * 2;
  u16* A2b   = (u16*)p;   p += (size_t)64 * 1024 * 2;
  float* part = (float*)p;  // [2][16384][8] f32 = 1 MB

  // ---- prep: weights only (~9 MB) ----
  prep_k<<<1864, 256, 0, stream>>>(Wb, rW1, rW2, loraA, loraB, Btb, W1b, W2b, A2b);

  // ---- gemm_h: h-GEMM + x->bf16 + partial router logits (writes xb, part) ----
  gemm_h<<<512, 512, 0, stream>>>(x, W1b, W2b, xb, part, rb1, 1024);

  // ---- w = (x @ A^T) * softmax(sum part + b2) -> bf16 [16384][64] ----
  gemm_w<<<dim3(1, M_TOK / 64), 256, 0, stream>>>(xb, A2b, part, rb2, temp, wb);

  // ---- out = [x | w] @ [Wb^T ; B2] -> f32, K=1088 (256^2, 8-phase) ----
  gemm_out<<<256, 512, 0, stream>>>(xb, Btb, wb, out, 1024, 1088, 1024, 1088);
}

// Round 18
// 90.129 us; speedup vs baseline: 1.0893x; 1.0893x over previous
//
#include <hip/hip_runtime.h>
#include <hip/hip_bf16.h>
#include <stdint.h>
#include <math.h>

// DynaLoRALinear bf16-MFMA.  (r15 best-known configuration, reverted from r16/r17.)
// prep(weights) -> gemm_h(full-N, fused x-convert + router softmax, K-rot)
//   -> gemm_w -> gemm_out(256^2, 8-phase counted-vmcnt).
// out = [x|w] @ [Wb^T;B2], K=1088.  GEMMs take K runtime (anti-unroll, r12).

#define M_TOK 16384

typedef unsigned short u16;
typedef short bf16x8 __attribute__((ext_vector_type(8)));
typedef float f32x4 __attribute__((ext_vector_type(4)));
typedef __attribute__((address_space(3))) uint32_t lds_u32_t;
typedef __attribute__((address_space(1))) const uint32_t glb_u32_t;

__device__ __forceinline__ u16 f2bf(float f) {
  uint32_t u = __builtin_bit_cast(uint32_t, f);
  return (u16)((u + 0x7fffu + ((u >> 16) & 1u)) >> 16);  // RNE
}
__device__ __forceinline__ int cvtpk(float lo, float hi) {  // RNE packed bf16
  int r;
  asm("v_cvt_pk_bf16_f32 %0, %1, %2" : "=v"(r) : "v"(lo), "v"(hi));
  return r;
}

#define VMCNT(n) asm volatile("s_waitcnt vmcnt(%0)" ::"i"(n) : "memory")
#define LGKM0 asm volatile("s_waitcnt lgkmcnt(0)" ::: "memory")
#define BAR asm volatile("s_barrier" ::: "memory")
#define MEMFENCE asm volatile("" ::: "memory")
#define SP(x) __builtin_amdgcn_s_setprio(x)

// ---------------- prep: weight conversions + gathers only (~9 MB) ----------------
__global__ __launch_bounds__(256) void prep_k(const float* __restrict__ Wb,
                                              const float* __restrict__ rW1,
                                              const float* __restrict__ rW2,
                                              const float* __restrict__ loraA,
                                              const float* __restrict__ loraB,
                                              u16* __restrict__ Btb,
                                              u16* __restrict__ W1b,
                                              u16* __restrict__ W2b,
                                              u16* __restrict__ A2b) {
  const int g = blockIdx.x;
  const int tid = threadIdx.x;
  if (g < 1024) {  // Wb -> Btb cols 0..1023 (stride 1088)
    int i = g * 256 + tid;
    int idx = i * 4;
    int row = idx >> 10, col = idx & 1023;
    float4 v = ((const float4*)Wb)[i];
    ushort4 o;
    o.x = f2bf(v.x); o.y = f2bf(v.y); o.z = f2bf(v.z); o.w = f2bf(v.w);
    *(ushort4*)(Btb + (size_t)row * 1088 + col) = o;
  } else if (g < 1536) {  // rW1 -> W1b
    int i = (g - 1024) * 256 + tid;
    float4 v = ((const float4*)rW1)[i];
    ushort4 o;
    o.x = f2bf(v.x); o.y = f2bf(v.y); o.z = f2bf(v.z); o.w = f2bf(v.w);
    ((ushort4*)W1b)[i] = o;
  } else if (g < 1792) {  // lora_B gather -> Btb cols 1024..1087
    int idx = (g - 1536) * 256 + tid;
    int n = idx >> 6, q = idx & 63;
    int e = q >> 3, r = q & 7;
    Btb[(size_t)n * 1088 + 1024 + q] = f2bf(loraB[((size_t)(e * 1024 + n)) * 8 + r]);
  } else if (g < 1856) {  // loraA -> A2b
    int i = (g - 1792) * 256 + tid;
    float4 v = ((const float4*)loraA)[i];
    ushort4 o;
    o.x = f2bf(v.x); o.y = f2bf(v.y); o.z = f2bf(v.z); o.w = f2bf(v.w);
    ((ushort4*)A2b)[i] = o;
  } else {  // W2b [16][512] bf16, rows 8..15 zero
    int i = (g - 1856) * 256 + tid;
    int idx = i * 4;
    int row = idx >> 9, col = idx & 511;
    ushort4 o = {0, 0, 0, 0};
    if (row < 8) {
      float4 v = *(const float4*)(rW2 + (size_t)row * 512 + col);
      o.x = f2bf(v.x); o.y = f2bf(v.y); o.z = f2bf(v.z); o.w = f2bf(v.w);
    }
    ((ushort4*)W2b)[i] = o;
  }
}

// ============ gemm_h: BM=64 x BN=512 (full N), fused x-convert + router ============
// (r15-proven form.)
__global__ __launch_bounds__(512, 2) void gemm_h(const float* __restrict__ x,
                                                 const u16* __restrict__ W1b,
                                                 const u16* __restrict__ W2bv,
                                                 u16* __restrict__ xb,
                                                 float* __restrict__ gates,
                                                 const float* __restrict__ b1,
                                                 const float* __restrict__ b2,
                                                 const float* __restrict__ temp,
                                                 const int K) {
  constexpr int ABUF = 64 * 128;           // 8 KB
  constexpr int BBUF = 512 * 128;          // 64 KB
  constexpr int BUFB = ABUF + BBUF;        // 72 KB
  __shared__ __align__(16) uint8_t lds[2 * BUFB];  // 144 KB

  const int tid = threadIdx.x;
  const int lane = tid & 63, w = tid >> 6;
  const int l15 = lane & 15, lhi = lane >> 4;
  const int xorv = (lane & 7) << 4;
  const int c0 = (lhi * 16) ^ xorv;
  const int c1 = (64 + lhi * 16) ^ xorv;

  const int f = blockIdx.x;
  const int m0 = ((f & 7) * 32 + (f >> 3)) * 64;

  const int nk = K >> 6;
  const int rot = (f >> 3) & (nk - 1);
  auto PH = [&](int l) { int lc = l < nk ? l : nk - 1; return (lc + rot) & (nk - 1); };

  const int xrow = tid >> 3, xsub = tid & 7;

  f32x4 acc[4][4] = {};
  bf16x8 af[4][2], bfv[4][2];
  float4 xA0, xA1, xB0, xB1;

  auto stageBH = [&](int ktp, int b) {
    uint8_t* dst = lds + b * BUFB + ABUF + w * 1024;
#pragma unroll
    for (int i = 0; i < 8; ++i) {
      const int off = i * 8192 + tid * 16;
      const int row = off >> 7;
      const int ss = ((off >> 4) & 7) ^ (row & 7);
      const uint8_t* g =
          (const uint8_t*)W1b + (size_t)row * 2048 + ktp * 128 + ss * 16;
      __builtin_amdgcn_global_load_lds((glb_u32_t*)g, (lds_u32_t*)(dst + i * 8192),
                                       16, 0, 0);
    }
  };
  auto issueX = [&](int ktp, float4& ra, float4& rb) {
    const float* gp = x + (size_t)(m0 + xrow) * 1024 + ktp * 64 + xsub * 8;
    ra = *(const float4*)gp;
    rb = *(const float4*)(gp + 4);
  };
  auto writeA = [&](int ktp, int b, const float4& ra, const float4& rb) {
    int4 sv;
    sv.x = cvtpk(ra.x, ra.y); sv.y = cvtpk(ra.z, ra.w);
    sv.z = cvtpk(rb.x, rb.y); sv.w = cvtpk(rb.z, rb.w);
    *(int4*)(lds + b * BUFB + xrow * 128 + ((xsub ^ (xrow & 7)) << 4)) = sv;
    *(int4*)(xb + (size_t)(m0 + xrow) * 1024 + ktp * 64 + xsub * 8) = sv;
  };
  auto loadAH = [&](const uint8_t* bufA) {
#pragma unroll
    for (int mf = 0; mf < 4; ++mf) {
      const uint8_t* pr = bufA + (mf * 16 + l15) * 128;
      af[mf][0] = *(const bf16x8*)(pr + c0);
      af[mf][1] = *(const bf16x8*)(pr + c1);
    }
  };
  auto loadBH = [&](const uint8_t* bufB) {
#pragma unroll
    for (int nf = 0; nf < 4; ++nf) {
      const uint8_t* pr = bufB + (w * 64 + nf * 16 + l15) * 128;
      bfv[nf][0] = *(const bf16x8*)(pr + c0);
      bfv[nf][1] = *(const bf16x8*)(pr + c1);
    }
  };

#define HMM()                                                                  \
  _Pragma("unroll") for (int mf = 0; mf < 4; ++mf)                             \
  _Pragma("unroll") for (int nf = 0; nf < 4; ++nf)                             \
  _Pragma("unroll") for (int ks = 0; ks < 2; ++ks)                             \
      acc[mf][nf] = __builtin_amdgcn_mfma_f32_16x16x32_bf16(                   \
          af[mf][ks], bfv[nf][ks], acc[mf][nf], 0, 0, 0);

  {
    const float* gp = x + (size_t)(m0 + xrow) * 1024 + rot * 64 + xsub * 8;
    float4 a = *(const float4*)gp, b = *(const float4*)(gp + 4);
    int4 sv;
    sv.x = cvtpk(a.x, a.y); sv.y = cvtpk(a.z, a.w);
    sv.z = cvtpk(b.x, b.y); sv.w = cvtpk(b.z, b.w);
    *(int4*)(lds + xrow * 128 + ((xsub ^ (xrow & 7)) << 4)) = sv;
    *(int4*)(xb + (size_t)(m0 + xrow) * 1024 + rot * 64 + xsub * 8) = sv;
  }
  stageBH(rot, 0);
  MEMFENCE;
  issueX(PH(1), xA0, xA1);
  VMCNT(2);
  LGKM0;
  BAR;

  const int nit = nk >> 1;
#pragma unroll 1
  for (int it = 0; it < nit; ++it) {
    const int t = it * 2;
    loadAH(lds);
    loadBH(lds + ABUF);
    stageBH(PH(t + 1), 1);
    MEMFENCE;
    issueX(PH(t + 2), xB0, xB1);
    MEMFENCE;
    VMCNT(10);
    writeA(PH(t + 1), 1, xA0, xA1);
    SP(1); HMM(); SP(0);
    LGKM0; VMCNT(3); BAR;
    loadAH(lds + BUFB);
    loadBH(lds + BUFB + ABUF);
    stageBH(PH(t + 2), 0);
    MEMFENCE;
    issueX(PH(t + 3), xA0, xA1);
    MEMFENCE;
    VMCNT(10);
    writeA(PH(t + 2), 0, xB0, xB1);
    SP(1); HMM(); SP(0);
    LGKM0; VMCNT(3); BAR;
  }

  u16* hs = (u16*)lds;
  __syncthreads();
#pragma unroll
  for (int mf = 0; mf < 4; ++mf) {
#pragma unroll
    for (int nf = 0; nf < 4; ++nf) {
      const int col = w * 64 + nf * 16 + l15;
#pragma unroll
      for (int j = 0; j < 4; ++j) {
        const int row = mf * 16 + lhi * 4 + j;
        float v = fmaxf(acc[mf][nf][j] + b1[col], 0.f);
        hs[row * 520 + col] = f2bf(v);
      }
    }
  }
  __syncthreads();
  if (w < 4) {
    f32x4 acc2 = {};
#pragma unroll
    for (int ks = 0; ks < 16; ++ks) {
      bf16x8 bfrag = *(const bf16x8*)(W2bv + (size_t)l15 * 512 + ks * 32 + lhi * 8);
      bf16x8 afrag = *(const bf16x8*)(hs + (w * 16 + l15) * 520 + ks * 32 + lhi * 8);
      acc2 = __builtin_amdgcn_mfma_f32_16x16x32_bf16(afrag, bfrag, acc2, 0, 0, 0);
    }
    if (l15 < 8) {
      float t = temp[0];
      float lg[4];
#pragma unroll
      for (int j = 0; j < 4; ++j) lg[j] = (acc2[j] + b2[l15]) / t;
      float mx[4], sm[4];
#pragma unroll
      for (int j = 0; j < 4; ++j) mx[j] = lg[j];
#pragma unroll
      for (int m = 1; m <= 4; m <<= 1)
#pragma unroll
        for (int j = 0; j < 4; ++j) mx[j] = fmaxf(mx[j], __shfl_xor(mx[j], m));
#pragma unroll
      for (int j = 0; j < 4; ++j) { lg[j] = expf(lg[j] - mx[j]); sm[j] = lg[j]; }
#pragma unroll
      for (int m = 1; m <= 4; m <<= 1)
#pragma unroll
        for (int j = 0; j < 4; ++j) sm[j] += __shfl_xor(sm[j], m);
#pragma unroll
      for (int j = 0; j < 4; ++j)
        gates[(size_t)(m0 + w * 16 + lhi * 4 + j) * 8 + l15] = lg[j] / sm[j];
    }
  }
}

// ---------------- w-GEMM (gates precomputed) ----------------
__global__ __launch_bounds__(256) void gemm_w(const u16* __restrict__ A,
                                              const u16* __restrict__ Bt,
                                              const float* __restrict__ gates,
                                              u16* __restrict__ Cv) {
  constexpr int BM = 64, BN = 64, FM = 2, FN = 2, AI = 2, BI = 2;
  __shared__ u16 lds[(BM + BN) * 64];
  __shared__ float g_lds[64][8];
  u16* As = lds;
  u16* Bs = lds + BM * 64;

  const int tid = threadIdx.x;
  const int w = tid >> 6, lane = tid & 63;
  const int wr = w >> 1, wc = w & 1;
  const int m0 = blockIdx.y * BM;

  if (tid < 64) {
    const float4* gp = (const float4*)(gates + (size_t)(m0 + tid) * 8);
    float4 a = gp[0], b = gp[1];
    g_lds[tid][0] = a.x; g_lds[tid][1] = a.y; g_lds[tid][2] = a.z; g_lds[tid][3] = a.w;
    g_lds[tid][4] = b.x; g_lds[tid][5] = b.y; g_lds[tid][6] = b.z; g_lds[tid][7] = b.w;
  }

  const uint8_t* Ab = (const uint8_t*)A;
  const uint8_t* Bb = (const uint8_t*)Bt;
  f32x4 acc[FM][FN] = {};

  for (int kt = 0; kt < 16; ++kt) {
#pragma unroll
    for (int i = 0; i < AI; ++i) {
      const int lbase = (w * AI + i) * 1024;
      const int o = lbase + lane * 16;
      const int r = o >> 7, cb = o & 127;
      const uint8_t* g = Ab + (size_t)(m0 + r) * 2048 + (size_t)kt * 128 + cb;
      __builtin_amdgcn_global_load_lds((glb_u32_t*)g,
                                       (lds_u32_t*)((uint8_t*)As + lbase), 16, 0, 0);
    }
#pragma unroll
    for (int i = 0; i < BI; ++i) {
      const int lbase = (w * BI + i) * 1024;
      const int o = lbase + lane * 16;
      const int r = o >> 7, cb = o & 127;
      const uint8_t* g = Bb + (size_t)r * 2048 + (size_t)kt * 128 + cb;
      __builtin_amdgcn_global_load_lds((glb_u32_t*)g,
                                       (lds_u32_t*)((uint8_t*)Bs + lbase), 16, 0, 0);
    }
    __syncthreads();

    bf16x8 af[2][FM], bfv[2][FN];
#pragma unroll
    for (int ks = 0; ks < 2; ++ks) {
      const int col = ks * 32 + ((lane >> 4) << 3);
#pragma unroll
      for (int im = 0; im < FM; ++im) {
        const int row = wr * 32 + im * 16 + (lane & 15);
        af[ks][im] = *(const bf16x8*)(As + row * 64 + col);
      }
#pragma unroll
      for (int in_ = 0; in_ < FN; ++in_) {
        const int row = wc * 32 + in_ * 16 + (lane & 15);
        bfv[ks][in_] = *(const bf16x8*)(Bs + row * 64 + col);
      }
    }
#pragma unroll
    for (int ks = 0; ks < 2; ++ks)
#pragma unroll
      for (int im = 0; im < FM; ++im)
#pragma unroll
        for (int in_ = 0; in_ < FN; ++in_)
          acc[im][in_] = __builtin_amdgcn_mfma_f32_16x16x32_bf16(
              af[ks][im], bfv[ks][in_], acc[im][in_], 0, 0, 0);
    __syncthreads();
  }

#pragma unroll
  for (int im = 0; im < FM; ++im)
#pragma unroll
    for (int in_ = 0; in_ < FN; ++in_) {
      const int col = wc * 32 + in_ * 16 + (lane & 15);
#pragma unroll
      for (int j = 0; j < 4; ++j) {
        const int lrow = wr * 32 + im * 16 + ((lane >> 4) << 2) + j;
        float v = acc[im][in_][j] * g_lds[lrow][col >> 3];
        Cv[(size_t)(m0 + lrow) * 64 + col] = f2bf(v);
      }
    }
}

// ============ gemm_out: r13-proven 8-phase 256^2 (runtime args, rolled loop) ============
#define MFMA_Q2(mh, nh, AF, BF)                                                \
  _Pragma("unroll") for (int im2 = 0; im2 < 4; ++im2)                          \
  _Pragma("unroll") for (int in2 = 0; in2 < 2; ++in2)                          \
  _Pragma("unroll") for (int ks = 0; ks < 2; ++ks)                             \
      acc[(mh) * 4 + im2][(nh) * 2 + in2] =                                    \
          __builtin_amdgcn_mfma_f32_16x16x32_bf16(                             \
              AF[im2][ks], BF[in2][ks],                                        \
              acc[(mh) * 4 + im2][(nh) * 2 + in2], 0, 0, 0);

__global__ __launch_bounds__(512, 2) void gemm_out(const u16* __restrict__ A,
                                                   const u16* __restrict__ Bt,
                                                   const u16* __restrict__ A2,
                                                   float* __restrict__ C,
                                                   const int N, const int K,
                                                   const int lda, const int ldb) {
  constexpr int BM = 256, BN = 256;
  constexpr int VMC = 4;
  constexpr int BUFB = (BM + BN) * 128;

  __shared__ __align__(16) uint8_t lds[2 * BUFB];

  const int tid = threadIdx.x;
  const int lane = tid & 63, w = tid >> 6;
  const int wr = w >> 2, wcn = w & 3;
  const int l15 = lane & 15, lhi = lane >> 4;
  const int xorv = (lane & 7) << 4;
  const int c0 = (lhi * 16) ^ xorv;
  const int c1 = (64 + lhi * 16) ^ xorv;

  const int f = blockIdx.x;
  const int idx = (f & 7) * 32 + (f >> 3);
  const int gx = N / BN;
  const int m0 = (idx / gx) * BM;
  const int n0 = (idx % gx) * BN;

  const size_t lda_b = (size_t)lda * 2, ldb_b = (size_t)ldb * 2;
  const int nk = K >> 6;
  const int arow0 = (wr * (BM / 2) + l15) * 128;
  const int brow0 = (wcn * (BN / 4) + l15) * 128;

  f32x4 acc[8][4] = {};
  bf16x8 A0f[4][2], A1f[4][2];
  bf16x8 B0f[2][2], B1f[2][2];

  auto stageA = [&](int h, int kt, int b) {
    const int ktc = kt < nk ? kt : nk - 1;
    const bool last = (ktc == nk - 1);
    uint8_t* dst = lds + b * BUFB + h * (BM * 64) + w * 1024;
#pragma unroll
    for (int i = 0; i < 2; ++i) {
      const int off = i * 8192 + tid * 16;
      const int row = h * (BM / 2) + (off >> 7);
      const int ss = ((off >> 4) & 7) ^ (row & 7);
      const uint8_t* g =
          last ? (const uint8_t*)A2 + (size_t)(m0 + row) * 128 + ss * 16
               : (const uint8_t*)A + (size_t)(m0 + row) * lda_b + ktc * 128 + ss * 16;
      __builtin_amdgcn_global_load_lds((glb_u32_t*)g, (lds_u32_t*)(dst + i * 8192),
                                       16, 0, 0);
    }
  };
  auto stageB = [&](int h, int kt, int b) {
    const int ktc = kt < nk ? kt : nk - 1;
    uint8_t* dst = lds + b * BUFB + BM * 128 + h * (BN * 64) + w * 1024;
#pragma unroll
    for (int i = 0; i < 2; ++i) {
      const int off = i * 8192 + tid * 16;
      const int row = h * (BN / 2) + (off >> 7);
      const int ss = ((off >> 4) & 7) ^ (row & 7);
      const uint8_t* g =
          (const uint8_t*)Bt + (size_t)(n0 + row) * ldb_b + ktc * 128 + ss * 16;
      __builtin_amdgcn_global_load_lds((glb_u32_t*)g, (lds_u32_t*)(dst + i * 8192),
                                       16, 0, 0);
    }
  };
  auto loadA = [&](int mh, const uint8_t* buf, bf16x8 (&dst)[4][2]) {
#pragma unroll
    for (int im2 = 0; im2 < 4; ++im2) {
      const uint8_t* p = buf + arow0 + mh * (4 * 2048) + im2 * 2048;
      dst[im2][0] = *(const bf16x8*)(p + c0);
      dst[im2][1] = *(const bf16x8*)(p + c1);
    }
  };
  auto loadB = [&](int nh, const uint8_t* buf, bf16x8 (&dst)[2][2]) {
#pragma unroll
    for (int in2 = 0; in2 < 2; ++in2) {
      const uint8_t* p = buf + BM * 128 + brow0 + nh * (2 * 2048) + in2 * 2048;
      dst[in2][0] = *(const bf16x8*)(p + c0);
      dst[in2][1] = *(const bf16x8*)(p + c1);
    }
  };

  const uint8_t* b0 = lds;
  const uint8_t* b1 = lds + BUFB;

  stageA(0, 0, 0); stageA(1, 0, 0);
  stageB(0, 0, 0); stageB(1, 0, 0);
  stageB(0, 1, 1); stageB(1, 1, 1);
  VMCNT(VMC); BAR;
  loadA(0, b0, A0f); loadB(0, b0, B0f);

  const int NIT = nk >> 1;
#pragma unroll 1
  for (int it = 0; it < NIT; ++it) {
    const int t = it * 2;
    // P1
    stageA(0, t + 1, 1);
    BAR;
    SP(1); MFMA_Q2(0, 0, A0f, B0f); SP(0);
    loadB(1, b0, B1f);
    BAR;
    // P2
    stageA(1, t + 1, 1);
    BAR;
    SP(1); MFMA_Q2(0, 1, A0f, B1f); SP(0);
    loadA(1, b0, A1f);
    BAR;
    // P3
    stageB(0, t + 2, 0);
    BAR;
    SP(1); MFMA_Q2(1, 1, A1f, B1f); SP(0);
    BAR;
    // P4
    stageB(1, t + 2, 0);
    VMCNT(VMC);
    BAR;
    SP(1); MFMA_Q2(1, 0, A1f, B0f); SP(0);
    loadA(0, b1, A0f); loadB(0, b1, B0f);
    BAR;
    // P5
    stageA(0, t + 2, 0);
    BAR;
    SP(1); MFMA_Q2(0, 0, A0f, B0f); SP(0);
    loadB(1, b1, B1f);
    BAR;
    // P6
    stageA(1, t + 2, 0);
    BAR;
    SP(1); MFMA_Q2(0, 1, A0f, B1f); SP(0);
    loadA(1, b1, A1f);
    BAR;
    // P7
    stageB(0, t + 3, 1);
    BAR;
    SP(1); MFMA_Q2(1, 1, A1f, B1f); SP(0);
    BAR;
    // P8
    stageB(1, t + 3, 1);
    VMCNT(VMC);
    BAR;
    SP(1); MFMA_Q2(1, 0, A1f, B0f); SP(0);
    loadA(0, b0, A0f); loadB(0, b0, B0f);
    BAR;
  }

  // tail K-tile (odd nk): buf0 holds tile nk-1; A0f/B0f pre-read at last P8
  if (nk & 1) {
    SP(1); MFMA_Q2(0, 0, A0f, B0f); SP(0);
    loadB(1, b0, B1f);
    SP(1); MFMA_Q2(0, 1, A0f, B1f); SP(0);
    loadA(1, b0, A1f);
    SP(1); MFMA_Q2(1, 1, A1f, B1f); MFMA_Q2(1, 0, A1f, B0f); SP(0);
  }

  // epilogue: plain f32 stores, C/D map col=lane&15, row=(lane>>4)*4+j
#pragma unroll
  for (int im = 0; im < 8; ++im) {
#pragma unroll
    for (int in_ = 0; in_ < 4; ++in_) {
      const int col = n0 + wcn * 64 + in_ * 16 + l15;
#pragma unroll
      for (int j = 0; j < 4; ++j) {
        const int row = m0 + wr * 128 + im * 16 + lhi * 4 + j;
        C[(size_t)row * N + col] = acc[im][in_][j];
      }
    }
  }
}

extern "C" void kernel_launch(void* const* d_in, const int* in_sizes, int n_in,
                              void* d_out, int out_size, void* d_ws, size_t ws_size,
                              hipStream_t stream) {
  const float* x     = (const float*)d_in[0];  // [16384][1024]
  const float* Wb    = (const float*)d_in[1];  // [1024][1024]
  const float* rW1   = (const float*)d_in[2];  // [512][1024]
  const float* rb1   = (const float*)d_in[3];  // [512]
  const float* rW2   = (const float*)d_in[4];  // [8][512]
  const float* rb2   = (const float*)d_in[5];  // [8]
  const float* temp  = (const float*)d_in[6];  // [1]
  const float* loraA = (const float*)d_in[7];  // [64][1024]
  const float* loraB = (const float*)d_in[8];  // [8][1024][8]
  float* out = (float*)d_out;

  uint8_t* p = (uint8_t*)d_ws;
  u16* xb    = (u16*)p;   p += (size_t)M_TOK * 1024 * 2;
  u16* wb    = (u16*)p;   p += (size_t)M_TOK * 64 * 2;
  u16* Btb   = (u16*)p;   p += (size_t)1024 * 1088 * 2;
  u16* W1b   = (u16*)p;   p += (size_t)512 * 1024 * 2;
  u16* W2b   = (u16*)p;   p += (size_t)16 * 512 * 2;
  u16* A2b   = (u16*)p;   p += (size_t)64 * 1024 * 2;
  float* gates = (float*)p;  // [16384][8] f32 = 512 KB

  // ---- prep: weights only (~9 MB) ----
  prep_k<<<1864, 256, 0, stream>>>(Wb, rW1, rW2, loraA, loraB, Btb, W1b, W2b, A2b);

  // ---- gemm_h: h-GEMM + x->bf16 + router logits/softmax (writes xb, gates) ----
  gemm_h<<<256, 512, 0, stream>>>(x, W1b, W2b, xb, gates, rb1, rb2, temp, 1024);

  // ---- w = (x @ A^T) * gates -> bf16 [16384][64] ----
  gemm_w<<<dim3(1, M_TOK / 64), 256, 0, stream>>>(xb, A2b, gates, wb);

  // ---- out = [x | w] @ [Wb^T ; B2] -> f32, K=1088 (256^2, 8-phase) ----
  gemm_out<<<256, 512, 0, stream>>>(xb, Btb, wb, out, 1024, 1088, 1024, 1088);
}

// Round 19
// 81.545 us; speedup vs baseline: 1.2040x; 1.1053x over previous
//
#include <hip/hip_runtime.h>
#include <hip/hip_bf16.h>
#include <stdint.h>
#include <math.h>

// DynaLoRALinear bf16-MFMA, 3-kernel pipeline.
// prep(weights) -> gemm_h(full-N h-GEMM + x-convert + router softmax + fused
// w=(x@A2^T)*gate) -> gemm_out(256^2, 8-phase).  out = [x|w] @ [Wb^T;B2], K=1088.

#define M_TOK 16384

typedef unsigned short u16;
typedef short bf16x8 __attribute__((ext_vector_type(8)));
typedef float f32x4 __attribute__((ext_vector_type(4)));
typedef __attribute__((address_space(3))) uint32_t lds_u32_t;
typedef __attribute__((address_space(1))) const uint32_t glb_u32_t;

__device__ __forceinline__ u16 f2bf(float f) {
  uint32_t u = __builtin_bit_cast(uint32_t, f);
  return (u16)((u + 0x7fffu + ((u >> 16) & 1u)) >> 16);  // RNE
}
__device__ __forceinline__ int cvtpk(float lo, float hi) {  // RNE packed bf16
  int r;
  asm("v_cvt_pk_bf16_f32 %0, %1, %2" : "=v"(r) : "v"(lo), "v"(hi));
  return r;
}

#define VMCNT(n) asm volatile("s_waitcnt vmcnt(%0)" ::"i"(n) : "memory")
#define LGKM0 asm volatile("s_waitcnt lgkmcnt(0)" ::: "memory")
#define BAR asm volatile("s_barrier" ::: "memory")
#define MEMFENCE asm volatile("" ::: "memory")
#define SP(x) __builtin_amdgcn_s_setprio(x)

// ---------------- prep: weight conversions + gathers only (~9 MB) ----------------
__global__ __launch_bounds__(256) void prep_k(const float* __restrict__ Wb,
                                              const float* __restrict__ rW1,
                                              const float* __restrict__ rW2,
                                              const float* __restrict__ loraA,
                                              const float* __restrict__ loraB,
                                              u16* __restrict__ Btb,
                                              u16* __restrict__ W1b,
                                              u16* __restrict__ W2b,
                                              u16* __restrict__ A2b) {
  const int g = blockIdx.x;
  const int tid = threadIdx.x;
  if (g < 1024) {  // Wb -> Btb cols 0..1023 (stride 1088)
    int i = g * 256 + tid;
    int idx = i * 4;
    int row = idx >> 10, col = idx & 1023;
    float4 v = ((const float4*)Wb)[i];
    ushort4 o;
    o.x = f2bf(v.x); o.y = f2bf(v.y); o.z = f2bf(v.z); o.w = f2bf(v.w);
    *(ushort4*)(Btb + (size_t)row * 1088 + col) = o;
  } else if (g < 1536) {  // rW1 -> W1b
    int i = (g - 1024) * 256 + tid;
    float4 v = ((const float4*)rW1)[i];
    ushort4 o;
    o.x = f2bf(v.x); o.y = f2bf(v.y); o.z = f2bf(v.z); o.w = f2bf(v.w);
    ((ushort4*)W1b)[i] = o;
  } else if (g < 1792) {  // lora_B gather -> Btb cols 1024..1087
    int idx = (g - 1536) * 256 + tid;
    int n = idx >> 6, q = idx & 63;
    int e = q >> 3, r = q & 7;
    Btb[(size_t)n * 1088 + 1024 + q] = f2bf(loraB[((size_t)(e * 1024 + n)) * 8 + r]);
  } else if (g < 1856) {  // loraA -> A2b
    int i = (g - 1792) * 256 + tid;
    float4 v = ((const float4*)loraA)[i];
    ushort4 o;
    o.x = f2bf(v.x); o.y = f2bf(v.y); o.z = f2bf(v.z); o.w = f2bf(v.w);
    ((ushort4*)A2b)[i] = o;
  } else {  // W2b [16][512] bf16, rows 8..15 zero
    int i = (g - 1856) * 256 + tid;
    int idx = i * 4;
    int row = idx >> 9, col = idx & 511;
    ushort4 o = {0, 0, 0, 0};
    if (row < 8) {
      float4 v = *(const float4*)(rW2 + (size_t)row * 512 + col);
      o.x = f2bf(v.x); o.y = f2bf(v.y); o.z = f2bf(v.z); o.w = f2bf(v.w);
    }
    ((ushort4*)W2b)[i] = o;
  }
}

// ===== gemm_h: BM=64 x BN=512 (full N), fused x-convert + router + w-GEMM =====
// r15 schedule + A2 K-tile (8 KB) staged beside B; per tile +1 gload (VMCNT 10->11)
// and +8 MFMA/wave for wacc[4] = x-tile @ A2^T (r-frag w&3; waves duplicate across
// w>=4, only w<4 store). Epilogue: relu-h -> router logits -> softmax -> g_lds;
// wb = wacc * gate stored directly. gemm_w eliminated.
__global__ __launch_bounds__(512, 2) void gemm_h(const float* __restrict__ x,
                                                 const u16* __restrict__ W1b,
                                                 const u16* __restrict__ W2bv,
                                                 const u16* __restrict__ A2bv,
                                                 u16* __restrict__ xb,
                                                 u16* __restrict__ wb,
                                                 const float* __restrict__ b1,
                                                 const float* __restrict__ b2,
                                                 const float* __restrict__ temp,
                                                 const int K) {
  constexpr int ABUF = 64 * 128;            // 8 KB (x tile)
  constexpr int BBUF = 512 * 128;           // 64 KB (W1 tile)
  constexpr int A2BUF = 64 * 128;           // 8 KB (A2 tile)
  constexpr int BUFB = ABUF + BBUF + A2BUF; // 80 KB
  __shared__ __align__(16) uint8_t lds[2 * BUFB];  // 160 KB

  const int tid = threadIdx.x;
  const int lane = tid & 63, w = tid >> 6;
  const int l15 = lane & 15, lhi = lane >> 4;
  const int xorv = (lane & 7) << 4;
  const int c0 = (lhi * 16) ^ xorv;
  const int c1 = (64 + lhi * 16) ^ xorv;

  const int f = blockIdx.x;
  const int m0 = ((f & 7) * 32 + (f >> 3)) * 64;

  const int nk = K >> 6;
  const int rot = (f >> 3) & (nk - 1);
  auto PH = [&](int l) { int lc = l < nk ? l : nk - 1; return (lc + rot) & (nk - 1); };

  const int xrow = tid >> 3, xsub = tid & 7;

  f32x4 acc[4][4] = {};
  f32x4 wacc[4] = {};
  bf16x8 af[4][2], bfv[4][2], a2f[2];
  float4 xA0, xA1, xB0, xB1;

  auto stageBH = [&](int ktp, int b) {
    uint8_t* dst = lds + b * BUFB + ABUF + w * 1024;
#pragma unroll
    for (int i = 0; i < 8; ++i) {
      const int off = i * 8192 + tid * 16;
      const int row = off >> 7;
      const int ss = ((off >> 4) & 7) ^ (row & 7);
      const uint8_t* g =
          (const uint8_t*)W1b + (size_t)row * 2048 + ktp * 128 + ss * 16;
      __builtin_amdgcn_global_load_lds((glb_u32_t*)g, (lds_u32_t*)(dst + i * 8192),
                                       16, 0, 0);
    }
  };
  auto stageA2 = [&](int ktp, int b) {
    uint8_t* dst = lds + b * BUFB + ABUF + BBUF + w * 1024;
    const int off = tid * 16;
    const int row = off >> 7;
    const int ss = ((off >> 4) & 7) ^ (row & 7);
    const uint8_t* g =
        (const uint8_t*)A2bv + (size_t)row * 2048 + ktp * 128 + ss * 16;
    __builtin_amdgcn_global_load_lds((glb_u32_t*)g, (lds_u32_t*)dst, 16, 0, 0);
  };
  auto issueX = [&](int ktp, float4& ra, float4& rb) {
    const float* gp = x + (size_t)(m0 + xrow) * 1024 + ktp * 64 + xsub * 8;
    ra = *(const float4*)gp;
    rb = *(const float4*)(gp + 4);
  };
  auto writeA = [&](int ktp, int b, const float4& ra, const float4& rb) {
    int4 sv;
    sv.x = cvtpk(ra.x, ra.y); sv.y = cvtpk(ra.z, ra.w);
    sv.z = cvtpk(rb.x, rb.y); sv.w = cvtpk(rb.z, rb.w);
    *(int4*)(lds + b * BUFB + xrow * 128 + ((xsub ^ (xrow & 7)) << 4)) = sv;
    *(int4*)(xb + (size_t)(m0 + xrow) * 1024 + ktp * 64 + xsub * 8) = sv;
  };
  auto loadAH = [&](const uint8_t* bufA) {
#pragma unroll
    for (int mf = 0; mf < 4; ++mf) {
      const uint8_t* pr = bufA + (mf * 16 + l15) * 128;
      af[mf][0] = *(const bf16x8*)(pr + c0);
      af[mf][1] = *(const bf16x8*)(pr + c1);
    }
  };
  auto loadBH = [&](const uint8_t* bufB) {
#pragma unroll
    for (int nf = 0; nf < 4; ++nf) {
      const uint8_t* pr = bufB + (w * 64 + nf * 16 + l15) * 128;
      bfv[nf][0] = *(const bf16x8*)(pr + c0);
      bfv[nf][1] = *(const bf16x8*)(pr + c1);
    }
  };
  auto loadA2 = [&](const uint8_t* base) {
    const uint8_t* pr = base + ABUF + BBUF + ((w & 3) * 16 + l15) * 128;
    a2f[0] = *(const bf16x8*)(pr + c0);
    a2f[1] = *(const bf16x8*)(pr + c1);
  };

#define HMM()                                                                  \
  _Pragma("unroll") for (int mf = 0; mf < 4; ++mf)                             \
  _Pragma("unroll") for (int nf = 0; nf < 4; ++nf)                             \
  _Pragma("unroll") for (int ks = 0; ks < 2; ++ks)                             \
      acc[mf][nf] = __builtin_amdgcn_mfma_f32_16x16x32_bf16(                   \
          af[mf][ks], bfv[nf][ks], acc[mf][nf], 0, 0, 0);
#define WMM()                                                                  \
  _Pragma("unroll") for (int mf = 0; mf < 4; ++mf)                             \
  _Pragma("unroll") for (int ks = 0; ks < 2; ++ks)                             \
      wacc[mf] = __builtin_amdgcn_mfma_f32_16x16x32_bf16(                      \
          af[mf][ks], a2f[ks], wacc[mf], 0, 0, 0);

  // ---- prologue: A(rot)->buf0 (convert), B(rot)+A2(rot)->buf0, issue x ----
  {
    const float* gp = x + (size_t)(m0 + xrow) * 1024 + rot * 64 + xsub * 8;
    float4 a = *(const float4*)gp, b = *(const float4*)(gp + 4);
    int4 sv;
    sv.x = cvtpk(a.x, a.y); sv.y = cvtpk(a.z, a.w);
    sv.z = cvtpk(b.x, b.y); sv.w = cvtpk(b.z, b.w);
    *(int4*)(lds + xrow * 128 + ((xsub ^ (xrow & 7)) << 4)) = sv;
    *(int4*)(xb + (size_t)(m0 + xrow) * 1024 + rot * 64 + xsub * 8) = sv;
  }
  stageBH(rot, 0);
  stageA2(rot, 0);
  MEMFENCE;
  issueX(PH(1), xA0, xA1);
  VMCNT(2);  // queue S1+B8+A2'1+x2=12; completes S+B+A2; leaves x(1):2
  LGKM0;
  BAR;

  const int nit = nk >> 1;
#pragma unroll 1
  for (int it = 0; it < nit; ++it) {
    const int t = it * 2;
    // ---- even tile t: p=buf0, q=buf1 ----
    loadAH(lds);
    loadBH(lds + ABUF);
    loadA2(lds);
    stageBH(PH(t + 1), 1);
    stageA2(PH(t + 1), 1);
    MEMFENCE;
    issueX(PH(t + 2), xB0, xB1);
    MEMFENCE;
    VMCNT(11);              // completes x(t+1) (+S when present)
    writeA(PH(t + 1), 1, xA0, xA1);
    SP(1); HMM(); WMM(); SP(0);
    LGKM0; VMCNT(3); BAR;   // completes B(t+1)+A2(t+1); leaves x(t+2):2 + S:1
    // ---- odd tile t+1: p=buf1, q=buf0 ----
    loadAH(lds + BUFB);
    loadBH(lds + BUFB + ABUF);
    loadA2(lds + BUFB);
    stageBH(PH(t + 2), 0);
    stageA2(PH(t + 2), 0);
    MEMFENCE;
    issueX(PH(t + 3), xA0, xA1);
    MEMFENCE;
    VMCNT(11);
    writeA(PH(t + 2), 0, xB0, xB1);
    SP(1); HMM(); WMM(); SP(0);
    LGKM0; VMCNT(3); BAR;
  }

  // ---- epilogue ----
  u16* hs = (u16*)lds;                       // [64][520] bf16 = 66560 B
  float* g_lds = (float*)(lds + 66560);      // [64][8] f32 = 2 KB
  __syncthreads();  // drains in-flight clamped prefetches + barrier
#pragma unroll
  for (int mf = 0; mf < 4; ++mf) {
#pragma unroll
    for (int nf = 0; nf < 4; ++nf) {
      const int col = w * 64 + nf * 16 + l15;
#pragma unroll
      for (int j = 0; j < 4; ++j) {
        const int row = mf * 16 + lhi * 4 + j;
        float v = fmaxf(acc[mf][nf][j] + b1[col], 0.f);
        hs[row * 520 + col] = f2bf(v);
      }
    }
  }
  __syncthreads();
  if (w < 4) {  // router: wave w -> logits rows w*16..+15, K=512
    f32x4 acc2 = {};
#pragma unroll
    for (int ks = 0; ks < 16; ++ks) {
      bf16x8 bfrag = *(const bf16x8*)(W2bv + (size_t)l15 * 512 + ks * 32 + lhi * 8);
      bf16x8 afrag = *(const bf16x8*)(hs + (w * 16 + l15) * 520 + ks * 32 + lhi * 8);
      acc2 = __builtin_amdgcn_mfma_f32_16x16x32_bf16(afrag, bfrag, acc2, 0, 0, 0);
    }
    if (l15 < 8) {  // lane holds logit[row=w*16+lhi*4+j][e=l15]
      float t = temp[0];
      float lg[4];
#pragma unroll
      for (int j = 0; j < 4; ++j) lg[j] = (acc2[j] + b2[l15]) / t;
      float mx[4], sm[4];
#pragma unroll
      for (int j = 0; j < 4; ++j) mx[j] = lg[j];
#pragma unroll
      for (int m = 1; m <= 4; m <<= 1)
#pragma unroll
        for (int j = 0; j < 4; ++j) mx[j] = fmaxf(mx[j], __shfl_xor(mx[j], m));
#pragma unroll
      for (int j = 0; j < 4; ++j) { lg[j] = expf(lg[j] - mx[j]); sm[j] = lg[j]; }
#pragma unroll
      for (int m = 1; m <= 4; m <<= 1)
#pragma unroll
        for (int j = 0; j < 4; ++j) sm[j] += __shfl_xor(sm[j], m);
#pragma unroll
      for (int j = 0; j < 4; ++j)
        g_lds[(w * 16 + lhi * 4 + j) * 8 + l15] = lg[j] / sm[j];
    }
  }
  __syncthreads();
  if (w < 4) {  // wb = wacc * gate; wave w owns cols w*16..+15, all 64 rows
#pragma unroll
    for (int mf = 0; mf < 4; ++mf) {
#pragma unroll
      for (int j = 0; j < 4; ++j) {
        const int row = mf * 16 + lhi * 4 + j;
        const int col = w * 16 + l15;
        float v = wacc[mf][j] * g_lds[row * 8 + (col >> 3)];
        wb[(size_t)(m0 + row) * 64 + col] = f2bf(v);
      }
    }
  }
}

// ============ gemm_out: r13-proven 8-phase 256^2 (runtime args, rolled loop) ============
#define MFMA_Q2(mh, nh, AF, BF)                                                \
  _Pragma("unroll") for (int im2 = 0; im2 < 4; ++im2)                          \
  _Pragma("unroll") for (int in2 = 0; in2 < 2; ++in2)                          \
  _Pragma("unroll") for (int ks = 0; ks < 2; ++ks)                             \
      acc[(mh) * 4 + im2][(nh) * 2 + in2] =                                    \
          __builtin_amdgcn_mfma_f32_16x16x32_bf16(                             \
              AF[im2][ks], BF[in2][ks],                                        \
              acc[(mh) * 4 + im2][(nh) * 2 + in2], 0, 0, 0);

__global__ __launch_bounds__(512, 2) void gemm_out(const u16* __restrict__ A,
                                                   const u16* __restrict__ Bt,
                                                   const u16* __restrict__ A2,
                                                   float* __restrict__ C,
                                                   const int N, const int K,
                                                   const int lda, const int ldb) {
  constexpr int BM = 256, BN = 256;
  constexpr int VMC = 4;
  constexpr int BUFB = (BM + BN) * 128;

  __shared__ __align__(16) uint8_t lds[2 * BUFB];

  const int tid = threadIdx.x;
  const int lane = tid & 63, w = tid >> 6;
  const int wr = w >> 2, wcn = w & 3;
  const int l15 = lane & 15, lhi = lane >> 4;
  const int xorv = (lane & 7) << 4;
  const int c0 = (lhi * 16) ^ xorv;
  const int c1 = (64 + lhi * 16) ^ xorv;

  const int f = blockIdx.x;
  const int idx = (f & 7) * 32 + (f >> 3);
  const int gx = N / BN;
  const int m0 = (idx / gx) * BM;
  const int n0 = (idx % gx) * BN;

  const size_t lda_b = (size_t)lda * 2, ldb_b = (size_t)ldb * 2;
  const int nk = K >> 6;
  const int arow0 = (wr * (BM / 2) + l15) * 128;
  const int brow0 = (wcn * (BN / 4) + l15) * 128;

  f32x4 acc[8][4] = {};
  bf16x8 A0f[4][2], A1f[4][2];
  bf16x8 B0f[2][2], B1f[2][2];

  auto stageA = [&](int h, int kt, int b) {
    const int ktc = kt < nk ? kt : nk - 1;
    const bool last = (ktc == nk - 1);
    uint8_t* dst = lds + b * BUFB + h * (BM * 64) + w * 1024;
#pragma unroll
    for (int i = 0; i < 2; ++i) {
      const int off = i * 8192 + tid * 16;
      const int row = h * (BM / 2) + (off >> 7);
      const int ss = ((off >> 4) & 7) ^ (row & 7);
      const uint8_t* g =
          last ? (const uint8_t*)A2 + (size_t)(m0 + row) * 128 + ss * 16
               : (const uint8_t*)A + (size_t)(m0 + row) * lda_b + ktc * 128 + ss * 16;
      __builtin_amdgcn_global_load_lds((glb_u32_t*)g, (lds_u32_t*)(dst + i * 8192),
                                       16, 0, 0);
    }
  };
  auto stageB = [&](int h, int kt, int b) {
    const int ktc = kt < nk ? kt : nk - 1;
    uint8_t* dst = lds + b * BUFB + BM * 128 + h * (BN * 64) + w * 1024;
#pragma unroll
    for (int i = 0; i < 2; ++i) {
      const int off = i * 8192 + tid * 16;
      const int row = h * (BN / 2) + (off >> 7);
      const int ss = ((off >> 4) & 7) ^ (row & 7);
      const uint8_t* g =
          (const uint8_t*)Bt + (size_t)(n0 + row) * ldb_b + ktc * 128 + ss * 16;
      __builtin_amdgcn_global_load_lds((glb_u32_t*)g, (lds_u32_t*)(dst + i * 8192),
                                       16, 0, 0);
    }
  };
  auto loadA = [&](int mh, const uint8_t* buf, bf16x8 (&dst)[4][2]) {
#pragma unroll
    for (int im2 = 0; im2 < 4; ++im2) {
      const uint8_t* p = buf + arow0 + mh * (4 * 2048) + im2 * 2048;
      dst[im2][0] = *(const bf16x8*)(p + c0);
      dst[im2][1] = *(const bf16x8*)(p + c1);
    }
  };
  auto loadB = [&](int nh, const uint8_t* buf, bf16x8 (&dst)[2][2]) {
#pragma unroll
    for (int in2 = 0; in2 < 2; ++in2) {
      const uint8_t* p = buf + BM * 128 + brow0 + nh * (2 * 2048) + in2 * 2048;
      dst[in2][0] = *(const bf16x8*)(p + c0);
      dst[in2][1] = *(const bf16x8*)(p + c1);
    }
  };

  const uint8_t* b0 = lds;
  const uint8_t* b1 = lds + BUFB;

  stageA(0, 0, 0); stageA(1, 0, 0);
  stageB(0, 0, 0); stageB(1, 0, 0);
  stageB(0, 1, 1); stageB(1, 1, 1);
  VMCNT(VMC); BAR;
  loadA(0, b0, A0f); loadB(0, b0, B0f);

  const int NIT = nk >> 1;
#pragma unroll 1
  for (int it = 0; it < NIT; ++it) {
    const int t = it * 2;
    // P1
    stageA(0, t + 1, 1);
    BAR;
    SP(1); MFMA_Q2(0, 0, A0f, B0f); SP(0);
    loadB(1, b0, B1f);
    BAR;
    // P2
    stageA(1, t + 1, 1);
    BAR;
    SP(1); MFMA_Q2(0, 1, A0f, B1f); SP(0);
    loadA(1, b0, A1f);
    BAR;
    // P3
    stageB(0, t + 2, 0);
    BAR;
    SP(1); MFMA_Q2(1, 1, A1f, B1f); SP(0);
    BAR;
    // P4
    stageB(1, t + 2, 0);
    VMCNT(VMC);
    BAR;
    SP(1); MFMA_Q2(1, 0, A1f, B0f); SP(0);
    loadA(0, b1, A0f); loadB(0, b1, B0f);
    BAR;
    // P5
    stageA(0, t + 2, 0);
    BAR;
    SP(1); MFMA_Q2(0, 0, A0f, B0f); SP(0);
    loadB(1, b1, B1f);
    BAR;
    // P6
    stageA(1, t + 2, 0);
    BAR;
    SP(1); MFMA_Q2(0, 1, A0f, B1f); SP(0);
    loadA(1, b1, A1f);
    BAR;
    // P7
    stageB(0, t + 3, 1);
    BAR;
    SP(1); MFMA_Q2(1, 1, A1f, B1f); SP(0);
    BAR;
    // P8
    stageB(1, t + 3, 1);
    VMCNT(VMC);
    BAR;
    SP(1); MFMA_Q2(1, 0, A1f, B0f); SP(0);
    loadA(0, b0, A0f); loadB(0, b0, B0f);
    BAR;
  }

  // tail K-tile (odd nk): buf0 holds tile nk-1; A0f/B0f pre-read at last P8
  if (nk & 1) {
    SP(1); MFMA_Q2(0, 0, A0f, B0f); SP(0);
    loadB(1, b0, B1f);
    SP(1); MFMA_Q2(0, 1, A0f, B1f); SP(0);
    loadA(1, b0, A1f);
    SP(1); MFMA_Q2(1, 1, A1f, B1f); MFMA_Q2(1, 0, A1f, B0f); SP(0);
  }

  // epilogue: plain f32 stores, C/D map col=lane&15, row=(lane>>4)*4+j
#pragma unroll
  for (int im = 0; im < 8; ++im) {
#pragma unroll
    for (int in_ = 0; in_ < 4; ++in_) {
      const int col = n0 + wcn * 64 + in_ * 16 + l15;
#pragma unroll
      for (int j = 0; j < 4; ++j) {
        const int row = m0 + wr * 128 + im * 16 + lhi * 4 + j;
        C[(size_t)row * N + col] = acc[im][in_][j];
      }
    }
  }
}

extern "C" void kernel_launch(void* const* d_in, const int* in_sizes, int n_in,
                              void* d_out, int out_size, void* d_ws, size_t ws_size,
                              hipStream_t stream) {
  const float* x     = (const float*)d_in[0];  // [16384][1024]
  const float* Wb    = (const float*)d_in[1];  // [1024][1024]
  const float* rW1   = (const float*)d_in[2];  // [512][1024]
  const float* rb1   = (const float*)d_in[3];  // [512]
  const float* rW2   = (const float*)d_in[4];  // [8][512]
  const float* rb2   = (const float*)d_in[5];  // [8]
  const float* temp  = (const float*)d_in[6];  // [1]
  const float* loraA = (const float*)d_in[7];  // [64][1024]
  const float* loraB = (const float*)d_in[8];  // [8][1024][8]
  float* out = (float*)d_out;

  uint8_t* p = (uint8_t*)d_ws;
  u16* xb    = (u16*)p;   p += (size_t)M_TOK * 1024 * 2;
  u16* wb    = (u16*)p;   p += (size_t)M_TOK * 64 * 2;
  u16* Btb   = (u16*)p;   p += (size_t)1024 * 1088 * 2;
  u16* W1b   = (u16*)p;   p += (size_t)512 * 1024 * 2;
  u16* W2b   = (u16*)p;   p += (size_t)16 * 512 * 2;
  u16* A2b   = (u16*)p;   p += (size_t)64 * 1024 * 2;

  // ---- prep: weights only (~9 MB) ----
  prep_k<<<1864, 256, 0, stream>>>(Wb, rW1, rW2, loraA, loraB, Btb, W1b, W2b, A2b);

  // ---- gemm_h: h + x->bf16 + router softmax + fused w-GEMM (writes xb, wb) ----
  gemm_h<<<256, 512, 0, stream>>>(x, W1b, W2b, A2b, xb, wb, rb1, rb2, temp, 1024);

  // ---- out = [x | w] @ [Wb^T ; B2] -> f32, K=1088 (256^2, 8-phase) ----
  gemm_out<<<256, 512, 0, stream>>>(xb, Btb, wb, out, 1024, 1088, 1024, 1088);
}

// Round 20
// 80.907 us; speedup vs baseline: 1.2135x; 1.0079x over previous
//
#include <hip/hip_runtime.h>
#include <hip/hip_bf16.h>
#include <stdint.h>
#include <math.h>

// DynaLoRALinear bf16-MFMA, 3-kernel pipeline.
// prep(weights) -> gemm_h(full-N h-GEMM + x-convert + router softmax + fused
// w=(x@A2^T)*gate) -> gemm_out(256^2, 8-phase).  out = [x|w] @ [Wb^T;B2], K=1088.
// r20: stage issued at top of tile (B fetch overlaps LDS frag-read drain).

#define M_TOK 16384

typedef unsigned short u16;
typedef short bf16x8 __attribute__((ext_vector_type(8)));
typedef float f32x4 __attribute__((ext_vector_type(4)));
typedef __attribute__((address_space(3))) uint32_t lds_u32_t;
typedef __attribute__((address_space(1))) const uint32_t glb_u32_t;

__device__ __forceinline__ u16 f2bf(float f) {
  uint32_t u = __builtin_bit_cast(uint32_t, f);
  return (u16)((u + 0x7fffu + ((u >> 16) & 1u)) >> 16);  // RNE
}
__device__ __forceinline__ int cvtpk(float lo, float hi) {  // RNE packed bf16
  int r;
  asm("v_cvt_pk_bf16_f32 %0, %1, %2" : "=v"(r) : "v"(lo), "v"(hi));
  return r;
}

#define VMCNT(n) asm volatile("s_waitcnt vmcnt(%0)" ::"i"(n) : "memory")
#define LGKM0 asm volatile("s_waitcnt lgkmcnt(0)" ::: "memory")
#define BAR asm volatile("s_barrier" ::: "memory")
#define MEMFENCE asm volatile("" ::: "memory")
#define SP(x) __builtin_amdgcn_s_setprio(x)

// ---------------- prep: weight conversions + gathers only (~9 MB) ----------------
__global__ __launch_bounds__(256) void prep_k(const float* __restrict__ Wb,
                                              const float* __restrict__ rW1,
                                              const float* __restrict__ rW2,
                                              const float* __restrict__ loraA,
                                              const float* __restrict__ loraB,
                                              u16* __restrict__ Btb,
                                              u16* __restrict__ W1b,
                                              u16* __restrict__ W2b,
                                              u16* __restrict__ A2b) {
  const int g = blockIdx.x;
  const int tid = threadIdx.x;
  if (g < 1024) {  // Wb -> Btb cols 0..1023 (stride 1088)
    int i = g * 256 + tid;
    int idx = i * 4;
    int row = idx >> 10, col = idx & 1023;
    float4 v = ((const float4*)Wb)[i];
    ushort4 o;
    o.x = f2bf(v.x); o.y = f2bf(v.y); o.z = f2bf(v.z); o.w = f2bf(v.w);
    *(ushort4*)(Btb + (size_t)row * 1088 + col) = o;
  } else if (g < 1536) {  // rW1 -> W1b
    int i = (g - 1024) * 256 + tid;
    float4 v = ((const float4*)rW1)[i];
    ushort4 o;
    o.x = f2bf(v.x); o.y = f2bf(v.y); o.z = f2bf(v.z); o.w = f2bf(v.w);
    ((ushort4*)W1b)[i] = o;
  } else if (g < 1792) {  // lora_B gather -> Btb cols 1024..1087
    int idx = (g - 1536) * 256 + tid;
    int n = idx >> 6, q = idx & 63;
    int e = q >> 3, r = q & 7;
    Btb[(size_t)n * 1088 + 1024 + q] = f2bf(loraB[((size_t)(e * 1024 + n)) * 8 + r]);
  } else if (g < 1856) {  // loraA -> A2b
    int i = (g - 1792) * 256 + tid;
    float4 v = ((const float4*)loraA)[i];
    ushort4 o;
    o.x = f2bf(v.x); o.y = f2bf(v.y); o.z = f2bf(v.z); o.w = f2bf(v.w);
    ((ushort4*)A2b)[i] = o;
  } else {  // W2b [16][512] bf16, rows 8..15 zero
    int i = (g - 1856) * 256 + tid;
    int idx = i * 4;
    int row = idx >> 9, col = idx & 511;
    ushort4 o = {0, 0, 0, 0};
    if (row < 8) {
      float4 v = *(const float4*)(rW2 + (size_t)row * 512 + col);
      o.x = f2bf(v.x); o.y = f2bf(v.y); o.z = f2bf(v.z); o.w = f2bf(v.w);
    }
    ((ushort4*)W2b)[i] = o;
  }
}

// ===== gemm_h: BM=64 x BN=512 (full N), fused x-convert + router + w-GEMM =====
// r19-proven; stage moved to top of tile. Per tile: [stage B:8+A2:1][frag reads]
// [issue x:2][VMCNT(11) -> x(t+1)+S][cvt+writeA+store][40 MFMA][LGKM0 VMCNT(3) BAR].
// FIFO: enter [x:2,S:1]; +9 +2 = 14; VMCNT(11) completes oldest 3 = x+S;
// VMCNT(3) completes B+A2 (9). Epilogue: router softmax in-LDS, wb = wacc*gate.
__global__ __launch_bounds__(512, 2) void gemm_h(const float* __restrict__ x,
                                                 const u16* __restrict__ W1b,
                                                 const u16* __restrict__ W2bv,
                                                 const u16* __restrict__ A2bv,
                                                 u16* __restrict__ xb,
                                                 u16* __restrict__ wb,
                                                 const float* __restrict__ b1,
                                                 const float* __restrict__ b2,
                                                 const float* __restrict__ temp,
                                                 const int K) {
  constexpr int ABUF = 64 * 128;            // 8 KB (x tile)
  constexpr int BBUF = 512 * 128;           // 64 KB (W1 tile)
  constexpr int A2BUF = 64 * 128;           // 8 KB (A2 tile)
  constexpr int BUFB = ABUF + BBUF + A2BUF; // 80 KB
  __shared__ __align__(16) uint8_t lds[2 * BUFB];  // 160 KB

  const int tid = threadIdx.x;
  const int lane = tid & 63, w = tid >> 6;
  const int l15 = lane & 15, lhi = lane >> 4;
  const int xorv = (lane & 7) << 4;
  const int c0 = (lhi * 16) ^ xorv;
  const int c1 = (64 + lhi * 16) ^ xorv;

  const int f = blockIdx.x;
  const int m0 = ((f & 7) * 32 + (f >> 3)) * 64;

  const int nk = K >> 6;
  const int rot = (f >> 3) & (nk - 1);
  auto PH = [&](int l) { int lc = l < nk ? l : nk - 1; return (lc + rot) & (nk - 1); };

  const int xrow = tid >> 3, xsub = tid & 7;

  f32x4 acc[4][4] = {};
  f32x4 wacc[4] = {};
  bf16x8 af[4][2], bfv[4][2], a2f[2];
  float4 xA0, xA1, xB0, xB1;

  auto stageBH = [&](int ktp, int b) {
    uint8_t* dst = lds + b * BUFB + ABUF + w * 1024;
#pragma unroll
    for (int i = 0; i < 8; ++i) {
      const int off = i * 8192 + tid * 16;
      const int row = off >> 7;
      const int ss = ((off >> 4) & 7) ^ (row & 7);
      const uint8_t* g =
          (const uint8_t*)W1b + (size_t)row * 2048 + ktp * 128 + ss * 16;
      __builtin_amdgcn_global_load_lds((glb_u32_t*)g, (lds_u32_t*)(dst + i * 8192),
                                       16, 0, 0);
    }
  };
  auto stageA2 = [&](int ktp, int b) {
    uint8_t* dst = lds + b * BUFB + ABUF + BBUF + w * 1024;
    const int off = tid * 16;
    const int row = off >> 7;
    const int ss = ((off >> 4) & 7) ^ (row & 7);
    const uint8_t* g =
        (const uint8_t*)A2bv + (size_t)row * 2048 + ktp * 128 + ss * 16;
    __builtin_amdgcn_global_load_lds((glb_u32_t*)g, (lds_u32_t*)dst, 16, 0, 0);
  };
  auto issueX = [&](int ktp, float4& ra, float4& rb) {
    const float* gp = x + (size_t)(m0 + xrow) * 1024 + ktp * 64 + xsub * 8;
    ra = *(const float4*)gp;
    rb = *(const float4*)(gp + 4);
  };
  auto writeA = [&](int ktp, int b, const float4& ra, const float4& rb) {
    int4 sv;
    sv.x = cvtpk(ra.x, ra.y); sv.y = cvtpk(ra.z, ra.w);
    sv.z = cvtpk(rb.x, rb.y); sv.w = cvtpk(rb.z, rb.w);
    *(int4*)(lds + b * BUFB + xrow * 128 + ((xsub ^ (xrow & 7)) << 4)) = sv;
    *(int4*)(xb + (size_t)(m0 + xrow) * 1024 + ktp * 64 + xsub * 8) = sv;
  };
  auto loadAH = [&](const uint8_t* bufA) {
#pragma unroll
    for (int mf = 0; mf < 4; ++mf) {
      const uint8_t* pr = bufA + (mf * 16 + l15) * 128;
      af[mf][0] = *(const bf16x8*)(pr + c0);
      af[mf][1] = *(const bf16x8*)(pr + c1);
    }
  };
  auto loadBH = [&](const uint8_t* bufB) {
#pragma unroll
    for (int nf = 0; nf < 4; ++nf) {
      const uint8_t* pr = bufB + (w * 64 + nf * 16 + l15) * 128;
      bfv[nf][0] = *(const bf16x8*)(pr + c0);
      bfv[nf][1] = *(const bf16x8*)(pr + c1);
    }
  };
  auto loadA2 = [&](const uint8_t* base) {
    const uint8_t* pr = base + ABUF + BBUF + ((w & 3) * 16 + l15) * 128;
    a2f[0] = *(const bf16x8*)(pr + c0);
    a2f[1] = *(const bf16x8*)(pr + c1);
  };

#define HMM()                                                                  \
  _Pragma("unroll") for (int mf = 0; mf < 4; ++mf)                             \
  _Pragma("unroll") for (int nf = 0; nf < 4; ++nf)                             \
  _Pragma("unroll") for (int ks = 0; ks < 2; ++ks)                             \
      acc[mf][nf] = __builtin_amdgcn_mfma_f32_16x16x32_bf16(                   \
          af[mf][ks], bfv[nf][ks], acc[mf][nf], 0, 0, 0);
#define WMM()                                                                  \
  _Pragma("unroll") for (int mf = 0; mf < 4; ++mf)                             \
  _Pragma("unroll") for (int ks = 0; ks < 2; ++ks)                             \
      wacc[mf] = __builtin_amdgcn_mfma_f32_16x16x32_bf16(                      \
          af[mf][ks], a2f[ks], wacc[mf], 0, 0, 0);

  // ---- prologue: A(rot)->buf0 (convert), B(rot)+A2(rot)->buf0, issue x ----
  {
    const float* gp = x + (size_t)(m0 + xrow) * 1024 + rot * 64 + xsub * 8;
    float4 a = *(const float4*)gp, b = *(const float4*)(gp + 4);
    int4 sv;
    sv.x = cvtpk(a.x, a.y); sv.y = cvtpk(a.z, a.w);
    sv.z = cvtpk(b.x, b.y); sv.w = cvtpk(b.z, b.w);
    *(int4*)(lds + xrow * 128 + ((xsub ^ (xrow & 7)) << 4)) = sv;
    *(int4*)(xb + (size_t)(m0 + xrow) * 1024 + rot * 64 + xsub * 8) = sv;
  }
  stageBH(rot, 0);
  stageA2(rot, 0);
  MEMFENCE;
  issueX(PH(1), xA0, xA1);
  VMCNT(2);  // queue S1+B8+A2'1+x2=12; completes S+B+A2; leaves x(1):2
  LGKM0;
  BAR;

  const int nit = nk >> 1;
#pragma unroll 1
  for (int it = 0; it < nit; ++it) {
    const int t = it * 2;
    // ---- even tile t: p=buf0, q=buf1 ----
    stageBH(PH(t + 1), 1);          // issue B early: fetch flies under ds_reads
    stageA2(PH(t + 1), 1);
    MEMFENCE;
    loadAH(lds);
    loadBH(lds + ABUF);
    loadA2(lds);
    issueX(PH(t + 2), xB0, xB1);
    MEMFENCE;
    VMCNT(11);              // completes x(t+1)+S(t)
    writeA(PH(t + 1), 1, xA0, xA1);
    SP(1); HMM(); WMM(); SP(0);
    LGKM0; VMCNT(3); BAR;   // completes B(t+1)+A2(t+1); leaves x(t+2):2 + S:1
    // ---- odd tile t+1: p=buf1, q=buf0 ----
    stageBH(PH(t + 2), 0);
    stageA2(PH(t + 2), 0);
    MEMFENCE;
    loadAH(lds + BUFB);
    loadBH(lds + BUFB + ABUF);
    loadA2(lds + BUFB);
    issueX(PH(t + 3), xA0, xA1);
    MEMFENCE;
    VMCNT(11);
    writeA(PH(t + 2), 0, xB0, xB1);
    SP(1); HMM(); WMM(); SP(0);
    LGKM0; VMCNT(3); BAR;
  }

  // ---- epilogue ----
  u16* hs = (u16*)lds;                       // [64][520] bf16 = 66560 B
  float* g_lds = (float*)(lds + 66560);      // [64][8] f32 = 2 KB
  __syncthreads();  // drains in-flight clamped prefetches + barrier
#pragma unroll
  for (int mf = 0; mf < 4; ++mf) {
#pragma unroll
    for (int nf = 0; nf < 4; ++nf) {
      const int col = w * 64 + nf * 16 + l15;
#pragma unroll
      for (int j = 0; j < 4; ++j) {
        const int row = mf * 16 + lhi * 4 + j;
        float v = fmaxf(acc[mf][nf][j] + b1[col], 0.f);
        hs[row * 520 + col] = f2bf(v);
      }
    }
  }
  __syncthreads();
  if (w < 4) {  // router: wave w -> logits rows w*16..+15, K=512
    f32x4 acc2 = {};
#pragma unroll
    for (int ks = 0; ks < 16; ++ks) {
      bf16x8 bfrag = *(const bf16x8*)(W2bv + (size_t)l15 * 512 + ks * 32 + lhi * 8);
      bf16x8 afrag = *(const bf16x8*)(hs + (w * 16 + l15) * 520 + ks * 32 + lhi * 8);
      acc2 = __builtin_amdgcn_mfma_f32_16x16x32_bf16(afrag, bfrag, acc2, 0, 0, 0);
    }
    if (l15 < 8) {  // lane holds logit[row=w*16+lhi*4+j][e=l15]
      float t = temp[0];
      float lg[4];
#pragma unroll
      for (int j = 0; j < 4; ++j) lg[j] = (acc2[j] + b2[l15]) / t;
      float mx[4], sm[4];
#pragma unroll
      for (int j = 0; j < 4; ++j) mx[j] = lg[j];
#pragma unroll
      for (int m = 1; m <= 4; m <<= 1)
#pragma unroll
        for (int j = 0; j < 4; ++j) mx[j] = fmaxf(mx[j], __shfl_xor(mx[j], m));
#pragma unroll
      for (int j = 0; j < 4; ++j) { lg[j] = expf(lg[j] - mx[j]); sm[j] = lg[j]; }
#pragma unroll
      for (int m = 1; m <= 4; m <<= 1)
#pragma unroll
        for (int j = 0; j < 4; ++j) sm[j] += __shfl_xor(sm[j], m);
#pragma unroll
      for (int j = 0; j < 4; ++j)
        g_lds[(w * 16 + lhi * 4 + j) * 8 + l15] = lg[j] / sm[j];
    }
  }
  __syncthreads();
  if (w < 4) {  // wb = wacc * gate; wave w owns cols w*16..+15, all 64 rows
#pragma unroll
    for (int mf = 0; mf < 4; ++mf) {
#pragma unroll
      for (int j = 0; j < 4; ++j) {
        const int row = mf * 16 + lhi * 4 + j;
        const int col = w * 16 + l15;
        float v = wacc[mf][j] * g_lds[row * 8 + (col >> 3)];
        wb[(size_t)(m0 + row) * 64 + col] = f2bf(v);
      }
    }
  }
}

// ============ gemm_out: r13-proven 8-phase 256^2 (runtime args, rolled loop) ============
#define MFMA_Q2(mh, nh, AF, BF)                                                \
  _Pragma("unroll") for (int im2 = 0; im2 < 4; ++im2)                          \
  _Pragma("unroll") for (int in2 = 0; in2 < 2; ++in2)                          \
  _Pragma("unroll") for (int ks = 0; ks < 2; ++ks)                             \
      acc[(mh) * 4 + im2][(nh) * 2 + in2] =                                    \
          __builtin_amdgcn_mfma_f32_16x16x32_bf16(                             \
              AF[im2][ks], BF[in2][ks],                                        \
              acc[(mh) * 4 + im2][(nh) * 2 + in2], 0, 0, 0);

__global__ __launch_bounds__(512, 2) void gemm_out(const u16* __restrict__ A,
                                                   const u16* __restrict__ Bt,
                                                   const u16* __restrict__ A2,
                                                   float* __restrict__ C,
                                                   const int N, const int K,
                                                   const int lda, const int ldb) {
  constexpr int BM = 256, BN = 256;
  constexpr int VMC = 4;
  constexpr int BUFB = (BM + BN) * 128;

  __shared__ __align__(16) uint8_t lds[2 * BUFB];

  const int tid = threadIdx.x;
  const int lane = tid & 63, w = tid >> 6;
  const int wr = w >> 2, wcn = w & 3;
  const int l15 = lane & 15, lhi = lane >> 4;
  const int xorv = (lane & 7) << 4;
  const int c0 = (lhi * 16) ^ xorv;
  const int c1 = (64 + lhi * 16) ^ xorv;

  const int f = blockIdx.x;
  const int idx = (f & 7) * 32 + (f >> 3);
  const int gx = N / BN;
  const int m0 = (idx / gx) * BM;
  const int n0 = (idx % gx) * BN;

  const size_t lda_b = (size_t)lda * 2, ldb_b = (size_t)ldb * 2;
  const int nk = K >> 6;
  const int arow0 = (wr * (BM / 2) + l15) * 128;
  const int brow0 = (wcn * (BN / 4) + l15) * 128;

  f32x4 acc[8][4] = {};
  bf16x8 A0f[4][2], A1f[4][2];
  bf16x8 B0f[2][2], B1f[2][2];

  auto stageA = [&](int h, int kt, int b) {
    const int ktc = kt < nk ? kt : nk - 1;
    const bool last = (ktc == nk - 1);
    uint8_t* dst = lds + b * BUFB + h * (BM * 64) + w * 1024;
#pragma unroll
    for (int i = 0; i < 2; ++i) {
      const int off = i * 8192 + tid * 16;
      const int row = h * (BM / 2) + (off >> 7);
      const int ss = ((off >> 4) & 7) ^ (row & 7);
      const uint8_t* g =
          last ? (const uint8_t*)A2 + (size_t)(m0 + row) * 128 + ss * 16
               : (const uint8_t*)A + (size_t)(m0 + row) * lda_b + ktc * 128 + ss * 16;
      __builtin_amdgcn_global_load_lds((glb_u32_t*)g, (lds_u32_t*)(dst + i * 8192),
                                       16, 0, 0);
    }
  };
  auto stageB = [&](int h, int kt, int b) {
    const int ktc = kt < nk ? kt : nk - 1;
    uint8_t* dst = lds + b * BUFB + BM * 128 + h * (BN * 64) + w * 1024;
#pragma unroll
    for (int i = 0; i < 2; ++i) {
      const int off = i * 8192 + tid * 16;
      const int row = h * (BN / 2) + (off >> 7);
      const int ss = ((off >> 4) & 7) ^ (row & 7);
      const uint8_t* g =
          (const uint8_t*)Bt + (size_t)(n0 + row) * ldb_b + ktc * 128 + ss * 16;
      __builtin_amdgcn_global_load_lds((glb_u32_t*)g, (lds_u32_t*)(dst + i * 8192),
                                       16, 0, 0);
    }
  };
  auto loadA = [&](int mh, const uint8_t* buf, bf16x8 (&dst)[4][2]) {
#pragma unroll
    for (int im2 = 0; im2 < 4; ++im2) {
      const uint8_t* p = buf + arow0 + mh * (4 * 2048) + im2 * 2048;
      dst[im2][0] = *(const bf16x8*)(p + c0);
      dst[im2][1] = *(const bf16x8*)(p + c1);
    }
  };
  auto loadB = [&](int nh, const uint8_t* buf, bf16x8 (&dst)[2][2]) {
#pragma unroll
    for (int in2 = 0; in2 < 2; ++in2) {
      const uint8_t* p = buf + BM * 128 + brow0 + nh * (2 * 2048) + in2 * 2048;
      dst[in2][0] = *(const bf16x8*)(p + c0);
      dst[in2][1] = *(const bf16x8*)(p + c1);
    }
  };

  const uint8_t* b0 = lds;
  const uint8_t* b1 = lds + BUFB;

  stageA(0, 0, 0); stageA(1, 0, 0);
  stageB(0, 0, 0); stageB(1, 0, 0);
  stageB(0, 1, 1); stageB(1, 1, 1);
  VMCNT(VMC); BAR;
  loadA(0, b0, A0f); loadB(0, b0, B0f);

  const int NIT = nk >> 1;
#pragma unroll 1
  for (int it = 0; it < NIT; ++it) {
    const int t = it * 2;
    // P1
    stageA(0, t + 1, 1);
    BAR;
    SP(1); MFMA_Q2(0, 0, A0f, B0f); SP(0);
    loadB(1, b0, B1f);
    BAR;
    // P2
    stageA(1, t + 1, 1);
    BAR;
    SP(1); MFMA_Q2(0, 1, A0f, B1f); SP(0);
    loadA(1, b0, A1f);
    BAR;
    // P3
    stageB(0, t + 2, 0);
    BAR;
    SP(1); MFMA_Q2(1, 1, A1f, B1f); SP(0);
    BAR;
    // P4
    stageB(1, t + 2, 0);
    VMCNT(VMC);
    BAR;
    SP(1); MFMA_Q2(1, 0, A1f, B0f); SP(0);
    loadA(0, b1, A0f); loadB(0, b1, B0f);
    BAR;
    // P5
    stageA(0, t + 2, 0);
    BAR;
    SP(1); MFMA_Q2(0, 0, A0f, B0f); SP(0);
    loadB(1, b1, B1f);
    BAR;
    // P6
    stageA(1, t + 2, 0);
    BAR;
    SP(1); MFMA_Q2(0, 1, A0f, B1f); SP(0);
    loadA(1, b1, A1f);
    BAR;
    // P7
    stageB(0, t + 3, 1);
    BAR;
    SP(1); MFMA_Q2(1, 1, A1f, B1f); SP(0);
    BAR;
    // P8
    stageB(1, t + 3, 1);
    VMCNT(VMC);
    BAR;
    SP(1); MFMA_Q2(1, 0, A1f, B0f); SP(0);
    loadA(0, b0, A0f); loadB(0, b0, B0f);
    BAR;
  }

  // tail K-tile (odd nk): buf0 holds tile nk-1; A0f/B0f pre-read at last P8
  if (nk & 1) {
    SP(1); MFMA_Q2(0, 0, A0f, B0f); SP(0);
    loadB(1, b0, B1f);
    SP(1); MFMA_Q2(0, 1, A0f, B1f); SP(0);
    loadA(1, b0, A1f);
    SP(1); MFMA_Q2(1, 1, A1f, B1f); MFMA_Q2(1, 0, A1f, B0f); SP(0);
  }

  // epilogue: plain f32 stores, C/D map col=lane&15, row=(lane>>4)*4+j
#pragma unroll
  for (int im = 0; im < 8; ++im) {
#pragma unroll
    for (int in_ = 0; in_ < 4; ++in_) {
      const int col = n0 + wcn * 64 + in_ * 16 + l15;
#pragma unroll
      for (int j = 0; j < 4; ++j) {
        const int row = m0 + wr * 128 + im * 16 + lhi * 4 + j;
        C[(size_t)row * N + col] = acc[im][in_][j];
      }
    }
  }
}

extern "C" void kernel_launch(void* const* d_in, const int* in_sizes, int n_in,
                              void* d_out, int out_size, void* d_ws, size_t ws_size,
                              hipStream_t stream) {
  const float* x     = (const float*)d_in[0];  // [16384][1024]
  const float* Wb    = (const float*)d_in[1];  // [1024][1024]
  const float* rW1   = (const float*)d_in[2];  // [512][1024]
  const float* rb1   = (const float*)d_in[3];  // [512]
  const float* rW2   = (const float*)d_in[4];  // [8][512]
  const float* rb2   = (const float*)d_in[5];  // [8]
  const float* temp  = (const float*)d_in[6];  // [1]
  const float* loraA = (const float*)d_in[7];  // [64][1024]
  const float* loraB = (const float*)d_in[8];  // [8][1024][8]
  float* out = (float*)d_out;

  uint8_t* p = (uint8_t*)d_ws;
  u16* xb    = (u16*)p;   p += (size_t)M_TOK * 1024 * 2;
  u16* wb    = (u16*)p;   p += (size_t)M_TOK * 64 * 2;
  u16* Btb   = (u16*)p;   p += (size_t)1024 * 1088 * 2;
  u16* W1b   = (u16*)p;   p += (size_t)512 * 1024 * 2;
  u16* W2b   = (u16*)p;   p += (size_t)16 * 512 * 2;
  u16* A2b   = (u16*)p;   p += (size_t)64 * 1024 * 2;

  // ---- prep: weights only (~9 MB) ----
  prep_k<<<1864, 256, 0, stream>>>(Wb, rW1, rW2, loraA, loraB, Btb, W1b, W2b, A2b);

  // ---- gemm_h: h + x->bf16 + router softmax + fused w-GEMM (writes xb, wb) ----
  gemm_h<<<256, 512, 0, stream>>>(x, W1b, W2b, A2b, xb, wb, rb1, rb2, temp, 1024);

  // ---- out = [x | w] @ [Wb^T ; B2] -> f32, K=1088 (256^2, 8-phase) ----
  gemm_out<<<256, 512, 0, stream>>>(xb, Btb, wb, out, 1024, 1088, 1024, 1088);
}